// Round 7
// baseline (2068.479 us; speedup 1.0000x reference)
//
#include <hip/hip_runtime.h>
#include <hip/hip_fp16.h>

static inline int ceil_div(int a, int b) { return (a + b - 1) / b; }

// ================= CSR build =================

__global__ void k_count_all(int NP, const int* __restrict__ dst_pp, int EPP,
                            const int* __restrict__ dst_pc, int EPC,
                            int* __restrict__ cnt1, int* __restrict__ cnt2) {
    int e = blockIdx.x * blockDim.x + threadIdx.x;
    if (e < NP) atomicAdd(&cnt1[e], 1);  // self loop
    if (e < EPP) atomicAdd(&cnt1[dst_pp[e]], 1);
    if (e < EPC) atomicAdd(&cnt2[dst_pc[e]], 1);
}

__global__ void k_scan1(const int* c1, int n1, int* i1, int* bs1,
                        const int* c2, int n2, int* i2, int* bs2) {
    const int* cnt = blockIdx.y ? c2 : c1;
    int n = blockIdx.y ? n2 : n1;
    int* incl = blockIdx.y ? i2 : i1;
    int* bsum = blockIdx.y ? bs2 : bs1;
    if ((int)blockIdx.x * 1024 >= n) return;
    __shared__ int sm[1024];
    int tid = threadIdx.x;
    int i = blockIdx.x * 1024 + tid;
    sm[tid] = (i < n) ? cnt[i] : 0;
    __syncthreads();
    for (int off = 1; off < 1024; off <<= 1) {
        int t = (tid >= off) ? sm[tid - off] : 0;
        __syncthreads();
        sm[tid] += t;
        __syncthreads();
    }
    if (i < n) incl[i] = sm[tid];
    if (tid == 1023) bsum[blockIdx.x] = sm[1023];
}

__global__ void k_scan2(int* bs1, int nb1, int* bs2, int nb2) {
    int* bsum = blockIdx.y ? bs2 : bs1;
    int nb = blockIdx.y ? nb2 : nb1;
    __shared__ int sm[1024];
    int tid = threadIdx.x;
    sm[tid] = (tid < nb) ? bsum[tid] : 0;
    __syncthreads();
    for (int off = 1; off < 1024; off <<= 1) {
        int t = (tid >= off) ? sm[tid - off] : 0;
        __syncthreads();
        sm[tid] += t;
        __syncthreads();
    }
    if (tid < nb) bsum[tid] = sm[tid];
}

// also initializes per-bucket staging cursors bcur[b] = offs[b*512]
__global__ void k_scan3(const int* c1, const int* i1, const int* bs1, int n1, int* o1, int* u1, int* bc1,
                        const int* c2, const int* i2, const int* bs2, int n2, int* o2, int* u2, int* bc2) {
    const int* cnt = blockIdx.y ? c2 : c1;
    const int* incl = blockIdx.y ? i2 : i1;
    const int* bsum = blockIdx.y ? bs2 : bs1;
    int n = blockIdx.y ? n2 : n1;
    int* offs = blockIdx.y ? o2 : o1;
    int* cur = blockIdx.y ? u2 : u1;
    int* bcur = blockIdx.y ? bc2 : bc1;
    int i = blockIdx.x * blockDim.x + threadIdx.x;
    if (i >= n) return;
    int b = i >> 10;
    int inc = incl[i] + (b ? bsum[b - 1] : 0);
    int off = inc - cnt[i];
    offs[i] = off;
    cur[i] = off;
    if ((i & 511) == 0) bcur[i >> 9] = off;
    if (i == n - 1) offs[n] = inc;
}

// Phase A: scatter edge records into dst-buckets (512 nodes/bucket). Bucket
// cursors advance sequentially -> line-coalesced 8B writes.
// record: .x = payload (pp: src<<7 byte offset; pc: src | fp16lab<<16), .y = dst
__global__ void k_bucketA(int NP,
                          const int* __restrict__ src_pp, const int* __restrict__ dst_pp, int EPP,
                          const int* __restrict__ src_pc, const int* __restrict__ dst_pc,
                          const float* __restrict__ lab, int EPC,
                          int* __restrict__ bcur1, int* __restrict__ bcur2,
                          uint2* __restrict__ stg1, uint2* __restrict__ stg2) {
    int e = blockIdx.x * blockDim.x + threadIdx.x;
    if (e < NP) {
        int pos = atomicAdd(&bcur1[e >> 9], 1);
        stg1[pos] = make_uint2((unsigned)e << 7, (unsigned)e);
    }
    if (e < EPP) {
        int d = dst_pp[e];
        int pos = atomicAdd(&bcur1[d >> 9], 1);
        stg1[pos] = make_uint2((unsigned)src_pp[e] << 7, (unsigned)d);
    }
    if (e < EPC) {
        int d = dst_pc[e];
        unsigned h = (unsigned)__half_as_ushort(__float2half_rn(lab[e]));
        int pos = atomicAdd(&bcur2[d >> 9], 1);
        stg2[pos] = make_uint2((unsigned)src_pc[e] | (h << 16), (unsigned)d);
    }
}

// Phase B: one workgroup per bucket; re-scatter into final CSR slots.
// Random writes confined to the bucket's ~32KB CSR window (L2-resident).
__global__ __launch_bounds__(256) void k_bucketB(
    int NB1, int NP, const int* __restrict__ off1, int* __restrict__ cur1,
    const uint2* __restrict__ stg1, unsigned* __restrict__ e1src,
    int NC, const int* __restrict__ off2, int* __restrict__ cur2,
    const uint2* __restrict__ stg2, unsigned* __restrict__ epay) {
    int b = blockIdx.x;
    if (b < NB1) {
        int n0 = b << 9;
        int n1 = (n0 + 512) < NP ? (n0 + 512) : NP;
        int lo = off1[n0], hi = off1[n1];
        for (int i = lo + threadIdx.x; i < hi; i += 256) {
            uint2 r = stg1[i];
            int pos = atomicAdd(&cur1[r.y], 1);
            e1src[pos] = r.x;
        }
    } else {
        int bb = b - NB1;
        int n0 = bb << 9;
        int n1 = (n0 + 512) < NC ? (n0 + 512) : NC;
        int lo = off2[n0], hi = off2[n1];
        for (int i = lo + threadIdx.x; i < hi; i += 256) {
            uint2 r = stg2[i];
            int pos = atomicAdd(&cur2[r.y], 1);
            epay[pos] = r.x;
        }
    }
}

// ================= weight transpose =================

__global__ void k_transpose_all(const float* s0, const float* s1, const float* s2,
                                const float* s3, float* __restrict__ wt) {
    const float* S[4] = {s0, s1, s2, s3};
    const float* W = S[blockIdx.y];
    int j = threadIdx.x, k = blockIdx.x;
    wt[blockIdx.y * 4096 + k * 64 + j] = W[j * 64 + k];
}

// ================= helpers =================

__device__ __forceinline__ unsigned pkh_(float a, float b) {
    __half2 h = __floats2half2_rn(a, b);
    return *(unsigned*)&h;
}

__device__ __forceinline__ uint2 ld8_(const void* p, unsigned boff) {
    return *(const uint2*)((const char*)p + boff);
}

__device__ __forceinline__ float4 unpk_(uint2 u) {
    __half2 h01 = *(__half2*)&u.x, h23 = *(__half2*)&u.y;
    float2 f01 = __half22float2(h01), f23 = __half22float2(h23);
    return make_float4(f01.x, f01.y, f23.x, f23.y);
}

// ================= fused input-transform GEMMs =================

__device__ __forceinline__ void gemm_one(const float xr[64], int row, bool valid,
                                         const float* __restrict__ WT,
                                         const float* __restrict__ b,
                                         void* __restrict__ o, int half_out) {
    for (int k4 = 0; k4 < 64; k4 += 4) {
        float a0 = b[k4 + 0], a1 = b[k4 + 1], a2 = b[k4 + 2], a3 = b[k4 + 3];
#pragma unroll
        for (int j = 0; j < 64; ++j) {
            float xv = xr[j];
            a0 = fmaf(xv, WT[(k4 + 0) * 64 + j], a0);
            a1 = fmaf(xv, WT[(k4 + 1) * 64 + j], a1);
            a2 = fmaf(xv, WT[(k4 + 2) * 64 + j], a2);
            a3 = fmaf(xv, WT[(k4 + 3) * 64 + j], a3);
        }
        if (valid) {
            if (half_out) {
                *(uint2*)((char*)o + (size_t)row * 128 + k4 * 2) =
                    make_uint2(pkh_(a0, a1), pkh_(a2, a3));
            } else {
                *(float4*)((float*)o + (size_t)row * 64 + k4) = make_float4(a0, a1, a2, a3);
            }
        }
    }
}

struct GemmJobs {
    const float* x[4]; const float* WT[4]; const float* b[4]; void* o[4];
    int n[4]; int tend[4]; int half_out[4];
};

__global__ __launch_bounds__(256) void k_gemm_all(GemmJobs J) {
    int lane = threadIdx.x & 63;
    int gtile = (blockIdx.x * blockDim.x + threadIdx.x) >> 6;
    if (gtile >= J.tend[3]) return;
    const float* x; const float* WT; const float* b; void* o; int n; int base; int ho;
    if (gtile < J.tend[0]) { x = J.x[0]; WT = J.WT[0]; b = J.b[0]; o = J.o[0]; n = J.n[0]; base = 0; ho = J.half_out[0]; }
    else if (gtile < J.tend[1]) { x = J.x[1]; WT = J.WT[1]; b = J.b[1]; o = J.o[1]; n = J.n[1]; base = J.tend[0]; ho = J.half_out[1]; }
    else if (gtile < J.tend[2]) { x = J.x[2]; WT = J.WT[2]; b = J.b[2]; o = J.o[2]; n = J.n[2]; base = J.tend[1]; ho = J.half_out[2]; }
    else { x = J.x[3]; WT = J.WT[3]; b = J.b[3]; o = J.o[3]; n = J.n[3]; base = J.tend[2]; ho = J.half_out[3]; }
    int row = (gtile - base) * 64 + lane;
    bool valid = row < n;
    int rr = valid ? row : 0;
    float xr[64];
    const float4* xp = (const float4*)(x + (size_t)rr * 64);
#pragma unroll
    for (int i = 0; i < 16; ++i) {
        float4 v = xp[i];
        xr[4 * i + 0] = v.x; xr[4 * i + 1] = v.y; xr[4 * i + 2] = v.z; xr[4 * i + 3] = v.w;
    }
    gemm_one(xr, row, valid, WT, b, o, ho);
}

// ================= GATv2 building blocks =================

__device__ __forceinline__ float leaky_(float x) { return fmaxf(x, 0.2f * x); }

template <int CTRL>
__device__ __forceinline__ float dppadd_(float x) {
    int y = __builtin_amdgcn_update_dpp(0, __float_as_int(x), CTRL, 0xF, 0xF, true);
    return x + __int_as_float(y);
}

// sum across each aligned 16-lane group (all lanes get the total); VALU-only
__device__ __forceinline__ float red16_(float c) {
    c = dppadd_<0xB1>(c);   // quad_perm xor1
    c = dppadd_<0x4E>(c);   // quad_perm xor2
    c = dppadd_<0x124>(c);  // row_ror:4
    c = dppadd_<0x128>(c);  // row_ror:8
    return c;
}

template <int HAS_EF>
__device__ __forceinline__ unsigned boff_(unsigned pr) {
    return HAS_EF ? ((pr & 0xFFFFu) << 7) : pr;  // pp payloads pre-shifted
}

// Edge loop over fp16 rows, no max-subtraction (scores O(+-5): fp32-safe),
// att4 pre-scaled by log2(e). slot = lane>>4 (4 edges in flight), g = lane&15.
// Payload prefetched 3 iterations ahead; feature gather 2 ahead.
template <int HAS_EF>
__device__ __forceinline__ void gat_pass(
    const void* __restrict__ hl, const unsigned* __restrict__ pay,
    int beg, int end, int slot, int g,
    float4 hr4, float4 att4, float4 we4,
    float& s_run, float4& acc) {
    s_run = 0.f;
    acc = make_float4(0.f, 0.f, 0.f, 0.f);
    if (beg >= end) return;
    unsigned goff = (unsigned)g * 8u;
    int last = end - 1;
    int p = beg + slot;
    int q0 = p < last ? p : last;
    int q1 = (p + 4) < last ? (p + 4) : last;
    int q2 = (p + 8) < last ? (p + 8) : last;
    unsigned pr0 = pay[q0], pr1 = pay[q1], pr2 = pay[q2], pr3;
    uint2 u0 = ld8_(hl, boff_<HAS_EF>(pr0) + goff);
    uint2 u1 = ld8_(hl, boff_<HAS_EF>(pr1) + goff);
    int pend = end + slot;
    for (; p < pend; p += 4) {
        int q3 = (p + 12) < last ? (p + 12) : last;
        pr3 = pay[q3];
        uint2 u2 = ld8_(hl, boff_<HAS_EF>(pr2) + goff);  // clamped: always safe
        float4 h = unpk_(u0);
        bool valid = p < end;
        float mx = h.x + hr4.x, my = h.y + hr4.y;
        float mz = h.z + hr4.z, mw = h.w + hr4.w;
        if (HAS_EF) {
            float lb = __half2float(__ushort_as_half((unsigned short)(pr0 >> 16)));
            mx = fmaf(lb, we4.x, mx); my = fmaf(lb, we4.y, my);
            mz = fmaf(lb, we4.z, mz); mw = fmaf(lb, we4.w, mw);
        }
        mx = leaky_(mx); my = leaky_(my); mz = leaky_(mz); mw = leaky_(mw);
        float c = mx * att4.x;
        c = fmaf(my, att4.y, c); c = fmaf(mz, att4.z, c); c = fmaf(mw, att4.w, c);
        c = red16_(c);
        float w = valid ? exp2f(c) : 0.f;
        s_run += w;
        acc.x = fmaf(w, h.x, acc.x);
        acc.y = fmaf(w, h.y, acc.y);
        acc.z = fmaf(w, h.z, acc.z);
        acc.w = fmaf(w, h.w, acc.w);
        pr0 = pr1; pr1 = pr2; pr2 = pr3; u0 = u1; u1 = u2;
    }
}

// cross-slot totals: pure butterfly adds
__device__ __forceinline__ void slot_merge(float& s, float4& a) {
#pragma unroll
    for (int mask = 16; mask <= 32; mask <<= 1) {
        s += __shfl_xor(s, mask, 64);
        a.x += __shfl_xor(a.x, mask, 64);
        a.y += __shfl_xor(a.y, mask, 64);
        a.z += __shfl_xor(a.z, mask, 64);
        a.w += __shfl_xor(a.w, mask, 64);
    }
}

__device__ __forceinline__ void finish_row(float s_run, float4 a,
                                           const float* __restrict__ bias, int g,
                                           float o4[4]) {
    float inv = 1.f / (s_run + 1e-16f);
    float4 b4 = *(const float4*)(bias + g * 4);
    o4[0] = fmaxf(fmaf(a.x, inv, b4.x), 0.f);
    o4[1] = fmaxf(fmaf(a.y, inv, b4.y), 0.f);
    o4[2] = fmaxf(fmaf(a.z, inv, b4.z), 0.f);
    o4[3] = fmaxf(fmaf(a.w, inv, b4.w), 0.f);
}

// In-wave GEMV row@W via LDS row broadcast: slot0 writes the 64-float row,
// each lane reads its slot's 16 j values (4x ds_read_b128), 64 fma, cross-slot
// butterfly. Same-wave LDS RAW: DS ops are in-order per wave; fences stop
// compiler reordering.
__device__ __forceinline__ float4 gemv64(const float o4[4], float* __restrict__ lds_row,
                                         int slot, int g, const float* __restrict__ W) {
    if (slot == 0) *(float4*)(lds_row + 4 * g) = make_float4(o4[0], o4[1], o4[2], o4[3]);
    __asm__ volatile("" ::: "memory");
    __builtin_amdgcn_wave_barrier();
    float4 r0 = *(const float4*)(lds_row + slot * 16 + 0);
    float4 r1 = *(const float4*)(lds_row + slot * 16 + 4);
    float4 r2 = *(const float4*)(lds_row + slot * 16 + 8);
    float4 r3 = *(const float4*)(lds_row + slot * 16 + 12);
    __asm__ volatile("" ::: "memory");
    __builtin_amdgcn_wave_barrier();
    float rv[16] = {r0.x, r0.y, r0.z, r0.w, r1.x, r1.y, r1.z, r1.w,
                    r2.x, r2.y, r2.z, r2.w, r3.x, r3.y, r3.z, r3.w};
    const float* Wp = W + slot * 16 * 64 + g * 4;
    float a0 = 0.f, a1 = 0.f, a2 = 0.f, a3 = 0.f;
#pragma unroll
    for (int t = 0; t < 16; ++t) {
        float4 w4 = *(const float4*)(Wp + t * 64);
        a0 = fmaf(rv[t], w4.x, a0); a1 = fmaf(rv[t], w4.y, a1);
        a2 = fmaf(rv[t], w4.z, a2); a3 = fmaf(rv[t], w4.w, a3);
    }
    a0 += __shfl_xor(a0, 16, 64); a0 += __shfl_xor(a0, 32, 64);
    a1 += __shfl_xor(a1, 16, 64); a1 += __shfl_xor(a1, 32, 64);
    a2 += __shfl_xor(a2, 16, 64); a2 += __shfl_xor(a2, 32, 64);
    a3 += __shfl_xor(a3, 16, 64); a3 += __shfl_xor(a3, 32, 64);
    return make_float4(a0, a1, a2, a3);
}

// conv1 (products): GAT + relu + @W3l + b3l -> hl3 (fp16)
__global__ __launch_bounds__(256) void k_gat1(
    const void* __restrict__ hl, const float* __restrict__ hr,
    const int* __restrict__ offs, const unsigned* __restrict__ esrc,
    const float* __restrict__ att, const float* __restrict__ bias,
    const float* __restrict__ W2, const float* __restrict__ b2,
    void* __restrict__ out2, int ndst) {
    __shared__ float rowbuf[4][64];
    int wid = (blockIdx.x * blockDim.x + threadIdx.x) >> 6;
    if (wid >= ndst) return;
    int lane = threadIdx.x & 63, slot = lane >> 4, g = lane & 15;
    float* lrow = rowbuf[threadIdx.x >> 6];
    float4 hr4 = *(const float4*)(hr + (size_t)wid * 64 + g * 4);
    float4 att4 = *(const float4*)(att + g * 4);
    att4.x *= 1.44269504f; att4.y *= 1.44269504f;
    att4.z *= 1.44269504f; att4.w *= 1.44269504f;
    int beg = offs[wid], end = offs[wid + 1];
    float s; float4 a;
    gat_pass<0>(hl, esrc, beg, end, slot, g, hr4, att4, att4, s, a);
    slot_merge(s, a);
    float o4[4];
    finish_row(s, a, bias, g, o4);
    float4 o = gemv64(o4, lrow, slot, g, W2);
    float4 bb = *(const float4*)(b2 + g * 4);
    o.x += bb.x; o.y += bb.y; o.z += bb.z; o.w += bb.w;
    if (slot == 0)
        *(uint2*)((char*)out2 + (size_t)wid * 128 + g * 8) =
            make_uint2(pkh_(o.x, o.y), pkh_(o.z, o.w));
}

// conv2 + conv3 fused per customer node
__global__ __launch_bounds__(256) void k_gat23(
    const void* __restrict__ hl2, const float* __restrict__ hr2,
    const void* __restrict__ hl3,
    const int* __restrict__ offs, const unsigned* __restrict__ epay,
    const float* __restrict__ We2, const float* __restrict__ att2, const float* __restrict__ bias2,
    const float* __restrict__ W3r, const float* __restrict__ b3r,
    const float* __restrict__ We3, const float* __restrict__ att3, const float* __restrict__ bias3,
    const float* __restrict__ Wlin, const float* __restrict__ blin,
    float* __restrict__ outp, int ndst) {
    __shared__ float rowbuf[4][64];
    int wid = (blockIdx.x * blockDim.x + threadIdx.x) >> 6;
    if (wid >= ndst) return;
    int lane = threadIdx.x & 63, slot = lane >> 4, g = lane & 15;
    float* lrow = rowbuf[threadIdx.x >> 6];
    int beg = offs[wid], end = offs[wid + 1];
    // ---- conv2 ----
    float4 hr4 = *(const float4*)(hr2 + (size_t)wid * 64 + g * 4);
    float4 att4 = *(const float4*)(att2 + g * 4);
    att4.x *= 1.44269504f; att4.y *= 1.44269504f;
    att4.z *= 1.44269504f; att4.w *= 1.44269504f;
    float4 we4 = *(const float4*)(We2 + g * 4);
    float s; float4 a;
    gat_pass<1>(hl2, epay, beg, end, slot, g, hr4, att4, we4, s, a);
    slot_merge(s, a);
    float o4[4];
    finish_row(s, a, bias2, g, o4);
    float4 h3 = gemv64(o4, lrow, slot, g, W3r);
    float4 bb = *(const float4*)(b3r + g * 4);
    h3.x += bb.x; h3.y += bb.y; h3.z += bb.z; h3.w += bb.w;
    // ---- conv3 ----
    att4 = *(const float4*)(att3 + g * 4);
    att4.x *= 1.44269504f; att4.y *= 1.44269504f;
    att4.z *= 1.44269504f; att4.w *= 1.44269504f;
    we4 = *(const float4*)(We3 + g * 4);
    gat_pass<1>(hl3, epay, beg, end, slot, g, h3, att4, we4, s, a);
    slot_merge(s, a);
    finish_row(s, a, bias3, g, o4);
    float4 o = gemv64(o4, lrow, slot, g, Wlin);
    float4 bl = *(const float4*)(blin + g * 4);
    o.x += bl.x; o.y += bl.y; o.z += bl.z; o.w += bl.w;
    if (slot == 0) *(float4*)(outp + (size_t)wid * 64 + g * 4) = o;
}

// ================= launch =================

extern "C" void kernel_launch(void* const* d_in, const int* in_sizes, int n_in,
                              void* d_out, int out_size, void* d_ws, size_t ws_size,
                              hipStream_t stream) {
    const float* x_p = (const float*)d_in[0];
    const float* x_c = (const float*)d_in[1];
    const float* elab_in = (const float*)d_in[2];
    const int* src_pp = (const int*)d_in[3];
    const int* dst_pp = (const int*)d_in[4];
    const int* src_pc = (const int*)d_in[5];
    const int* dst_pc = (const int*)d_in[6];
    const float* W1l = (const float*)d_in[7];
    const float* b1l = (const float*)d_in[8];
    const float* W1r = (const float*)d_in[9];
    const float* b1r = (const float*)d_in[10];
    const float* att1 = (const float*)d_in[11];
    const float* bias1 = (const float*)d_in[12];
    const float* W2l = (const float*)d_in[13];
    const float* b2l = (const float*)d_in[14];
    const float* W2r = (const float*)d_in[15];
    const float* b2r = (const float*)d_in[16];
    const float* We2 = (const float*)d_in[17];
    const float* att2 = (const float*)d_in[18];
    const float* bias2 = (const float*)d_in[19];
    const float* W3l = (const float*)d_in[20];
    const float* b3l = (const float*)d_in[21];
    const float* W3r = (const float*)d_in[22];
    const float* b3r = (const float*)d_in[23];
    const float* We3 = (const float*)d_in[24];
    const float* att3 = (const float*)d_in[25];
    const float* bias3 = (const float*)d_in[26];
    const float* Wlin = (const float*)d_in[27];
    const float* blin = (const float*)d_in[28];
    float* out = (float*)d_out;

    const int NP = in_sizes[0] / 64;
    const int NC = in_sizes[1] / 64;
    const int EPP = in_sizes[3];
    const int EPC = in_sizes[5];
    const int E1 = EPP + NP;
    const int NB1 = ceil_div(NP, 512), NB2 = ceil_div(NC, 512);

    // workspace layout (256B-aligned chunks)
    char* w = (char*)d_ws;
    auto alloc = [&](size_t bytes) { char* r = w; w += (bytes + 255) & ~(size_t)255; return r; };
    void* hl1 = alloc((size_t)NP * 128);       // fp16
    void* hl2 = alloc((size_t)NP * 128);       // fp16
    void* hl3 = alloc((size_t)NP * 128);       // fp16 (conv1-fused output)
    float* hr1 = (float*)alloc((size_t)NP * 256);
    float* hr2 = (float*)alloc((size_t)NC * 256);
    float* wt = (float*)alloc(4 * 4096 * 4);
    unsigned* epay = (unsigned*)alloc((size_t)EPC * 4);
    unsigned* e1src = (unsigned*)alloc((size_t)E1 * 4);
    uint2* stg1 = (uint2*)alloc((size_t)E1 * 8);
    uint2* stg2 = (uint2*)alloc((size_t)EPC * 8);
    int* off1 = (int*)alloc((size_t)(NP + 1) * 4);
    int* cnt1 = (int*)alloc((size_t)NP * 4);
    int* off2 = (int*)alloc((size_t)(NC + 1) * 4);
    int* cnt2 = (int*)alloc((size_t)NC * 4);
    int* incl1 = (int*)alloc((size_t)NP * 4);
    int* incl2 = (int*)alloc((size_t)NC * 4);
    int* bsum1 = (int*)alloc(1024 * 4);
    int* bsum2 = (int*)alloc(1024 * 4);
    int* bcur1 = (int*)alloc((size_t)NB1 * 4);
    int* bcur2 = (int*)alloc((size_t)NB2 * 4);

    int nb1 = ceil_div(NP, 1024), nb2 = ceil_div(NC, 1024);
    int maxE = EPC > EPP ? EPC : EPP; if (NP > maxE) maxE = NP;
    int maxN = NC > NP ? NC : NP;

    hipMemsetAsync(cnt1, 0, (size_t)NP * 4, stream);
    hipMemsetAsync(cnt2, 0, (size_t)NC * 4, stream);

    k_transpose_all<<<dim3(64, 4), 64, 0, stream>>>(W1l, W1r, W2l, W2r, wt);

    k_count_all<<<ceil_div(maxE, 256), 256, 0, stream>>>(NP, dst_pp, EPP, dst_pc, EPC, cnt1, cnt2);
    k_scan1<<<dim3(nb2 > nb1 ? nb2 : nb1, 2), 1024, 0, stream>>>(
        cnt1, NP, incl1, bsum1, cnt2, NC, incl2, bsum2);
    k_scan2<<<dim3(1, 2), 1024, 0, stream>>>(bsum1, nb1, bsum2, nb2);
    k_scan3<<<dim3(ceil_div(maxN, 256), 2), 256, 0, stream>>>(
        cnt1, incl1, bsum1, NP, off1, cnt1, bcur1,
        cnt2, incl2, bsum2, NC, off2, cnt2, bcur2);
    k_bucketA<<<ceil_div(maxE, 256), 256, 0, stream>>>(
        NP, src_pp, dst_pp, EPP, src_pc, dst_pc, elab_in, EPC, bcur1, bcur2, stg1, stg2);
    k_bucketB<<<NB1 + NB2, 256, 0, stream>>>(
        NB1, NP, off1, cnt1, stg1, e1src, NC, off2, cnt2, stg2, epay);

    // fused input transforms: hl1 = x_p@W1l (h), hr1 = x_p@W1r (f), hl2 = x_p@W2l (h), hr2 = x_c@W2r (f)
    int tp = ceil_div(NP, 64), tc = ceil_div(NC, 64);
    GemmJobs J;
    J.x[0] = x_p; J.WT[0] = wt + 0 * 4096; J.b[0] = b1l; J.o[0] = hl1; J.n[0] = NP; J.half_out[0] = 1;
    J.x[1] = x_p; J.WT[1] = wt + 1 * 4096; J.b[1] = b1r; J.o[1] = hr1; J.n[1] = NP; J.half_out[1] = 0;
    J.x[2] = x_p; J.WT[2] = wt + 2 * 4096; J.b[2] = b2l; J.o[2] = hl2; J.n[2] = NP; J.half_out[2] = 1;
    J.x[3] = x_c; J.WT[3] = wt + 3 * 4096; J.b[3] = b2r; J.o[3] = hr2; J.n[3] = NC; J.half_out[3] = 0;
    J.tend[0] = tp; J.tend[1] = 2 * tp; J.tend[2] = 3 * tp; J.tend[3] = 3 * tp + tc;
    k_gemm_all<<<ceil_div(J.tend[3] * 64, 256), 256, 0, stream>>>(J);

    // conv1 -> (relu -> @W3l + b3l) -> hl3 (fp16)
    k_gat1<<<ceil_div(NP * 64, 256), 256, 0, stream>>>(
        hl1, hr1, off1, e1src, att1, bias1, W3l, b3l, hl3, NP);

    // conv2+conv3 fused -> d_out
    k_gat23<<<ceil_div(NC * 64, 256), 256, 0, stream>>>(
        hl2, hr2, hl3, off2, epay, We2, att2, bias2, W3r, b3r,
        We3, att3, bias3, Wlin, blin, out, NC);
}

// Round 9
// 680.751 us; speedup vs baseline: 3.0385x; 3.0385x over previous
//
#include <hip/hip_runtime.h>
#include <hip/hip_fp16.h>

static inline int ceil_div(int a, int b) { return (a + b - 1) / b; }

typedef _Float16 f16x2 __attribute__((ext_vector_type(2)));

// ================= CSR build =================

__global__ void k_count_all(int NP, const int* __restrict__ dst_pp, int EPP,
                            const int* __restrict__ dst_pc, int EPC,
                            int* __restrict__ cnt1, int* __restrict__ cnt2) {
    int e = blockIdx.x * blockDim.x + threadIdx.x;
    if (e < NP) atomicAdd(&cnt1[e], 1);  // self loop
    if (e < EPP) atomicAdd(&cnt1[dst_pp[e]], 1);
    if (e < EPC) atomicAdd(&cnt2[dst_pc[e]], 1);
}

__global__ void k_scan1(const int* c1, int n1, int* i1, int* bs1,
                        const int* c2, int n2, int* i2, int* bs2) {
    const int* cnt = blockIdx.y ? c2 : c1;
    int n = blockIdx.y ? n2 : n1;
    int* incl = blockIdx.y ? i2 : i1;
    int* bsum = blockIdx.y ? bs2 : bs1;
    if ((int)blockIdx.x * 1024 >= n) return;
    __shared__ int sm[1024];
    int tid = threadIdx.x;
    int i = blockIdx.x * 1024 + tid;
    sm[tid] = (i < n) ? cnt[i] : 0;
    __syncthreads();
    for (int off = 1; off < 1024; off <<= 1) {
        int t = (tid >= off) ? sm[tid - off] : 0;
        __syncthreads();
        sm[tid] += t;
        __syncthreads();
    }
    if (i < n) incl[i] = sm[tid];
    if (tid == 1023) bsum[blockIdx.x] = sm[1023];
}

__global__ void k_scan2(int* bs1, int nb1, int* bs2, int nb2) {
    int* bsum = blockIdx.y ? bs2 : bs1;
    int nb = blockIdx.y ? nb2 : nb1;
    __shared__ int sm[1024];
    int tid = threadIdx.x;
    sm[tid] = (tid < nb) ? bsum[tid] : 0;
    __syncthreads();
    for (int off = 1; off < 1024; off <<= 1) {
        int t = (tid >= off) ? sm[tid - off] : 0;
        __syncthreads();
        sm[tid] += t;
        __syncthreads();
    }
    if (tid < nb) bsum[tid] = sm[tid];
}

__global__ void k_scan3(const int* c1, const int* i1, const int* bs1, int n1, int* o1, int* u1,
                        const int* c2, const int* i2, const int* bs2, int n2, int* o2, int* u2) {
    const int* cnt = blockIdx.y ? c2 : c1;
    const int* incl = blockIdx.y ? i2 : i1;
    const int* bsum = blockIdx.y ? bs2 : bs1;
    int n = blockIdx.y ? n2 : n1;
    int* offs = blockIdx.y ? o2 : o1;
    int* cur = blockIdx.y ? u2 : u1;
    int i = blockIdx.x * blockDim.x + threadIdx.x;
    if (i >= n) return;
    int b = i >> 10;
    int inc = incl[i] + (b ? bsum[b - 1] : 0);
    int off = inc - cnt[i];
    offs[i] = off;
    cur[i] = off;
    if (i == n - 1) offs[n] = inc;
}

// direct scatter, per-node cursors (150K counters: low contention).
// pp payload: src<<7 (byte offset of fp16 row). pc payload: src | fp16lab<<16.
// Also zero-pads 16 entries past each array end (for clamp-free prefetch).
__global__ void k_scatter_all(int NP,
                              const int* __restrict__ src_pp, const int* __restrict__ dst_pp, int EPP,
                              const int* __restrict__ src_pc, const int* __restrict__ dst_pc,
                              const float* __restrict__ lab, int EPC, int E1,
                              int* __restrict__ cur1, int* __restrict__ cur2,
                              unsigned* __restrict__ e1src, unsigned* __restrict__ epay) {
    int e = blockIdx.x * blockDim.x + threadIdx.x;
    if (e < 16) { e1src[E1 + e] = 0u; epay[EPC + e] = 0u; }
    if (e < NP) { int pos = atomicAdd(&cur1[e], 1); e1src[pos] = (unsigned)e << 7; }
    if (e < EPP) { int pos = atomicAdd(&cur1[dst_pp[e]], 1); e1src[pos] = (unsigned)src_pp[e] << 7; }
    if (e < EPC) {
        int pos = atomicAdd(&cur2[dst_pc[e]], 1);
        unsigned h = (unsigned)__half_as_ushort(__float2half_rn(lab[e]));
        epay[pos] = (unsigned)src_pc[e] | (h << 16);
    }
}

// ================= weight transpose =================

__global__ void k_transpose_all(const float* s0, const float* s1, const float* s2,
                                const float* s3, float* __restrict__ wt) {
    const float* S[4] = {s0, s1, s2, s3};
    const float* W = S[blockIdx.y];
    int j = threadIdx.x, k = blockIdx.x;
    wt[blockIdx.y * 4096 + k * 64 + j] = W[j * 64 + k];
}

// ================= helpers =================

__device__ __forceinline__ unsigned pkh_(float a, float b) {
    __half2 h = __floats2half2_rn(a, b);
    return *(unsigned*)&h;
}

__device__ __forceinline__ f16x2 pkc_(float a, float b) {
    f16x2 r;
    r.x = (_Float16)a;
    r.y = (_Float16)b;
    return r;
}

__device__ __forceinline__ uint2 ld8_(const void* p, unsigned boff) {
    return *(const uint2*)((const char*)p + boff);
}

__device__ __forceinline__ float4 unpk_(uint2 u) {
    f16x2 h01 = *(f16x2*)&u.x, h23 = *(f16x2*)&u.y;
    return make_float4((float)h01.x, (float)h01.y, (float)h23.x, (float)h23.y);
}

__device__ __forceinline__ float fdot2_(f16x2 a, f16x2 b, float c) {
#if __has_builtin(__builtin_amdgcn_fdot2)
    return __builtin_amdgcn_fdot2(a, b, c, false);
#else
    return fmaf((float)a.x, (float)b.x, fmaf((float)a.y, (float)b.y, c));
#endif
}

// ================= fused input-transform GEMMs =================

__device__ __forceinline__ void gemm_one(const float xr[64], int row, bool valid,
                                         const float* __restrict__ WT,
                                         const float* __restrict__ b,
                                         void* __restrict__ o, int half_out) {
    for (int k4 = 0; k4 < 64; k4 += 4) {
        float a0 = b[k4 + 0], a1 = b[k4 + 1], a2 = b[k4 + 2], a3 = b[k4 + 3];
#pragma unroll
        for (int j = 0; j < 64; ++j) {
            float xv = xr[j];
            a0 = fmaf(xv, WT[(k4 + 0) * 64 + j], a0);
            a1 = fmaf(xv, WT[(k4 + 1) * 64 + j], a1);
            a2 = fmaf(xv, WT[(k4 + 2) * 64 + j], a2);
            a3 = fmaf(xv, WT[(k4 + 3) * 64 + j], a3);
        }
        if (valid) {
            if (half_out) {
                *(uint2*)((char*)o + (size_t)row * 128 + k4 * 2) =
                    make_uint2(pkh_(a0, a1), pkh_(a2, a3));
            } else {
                *(float4*)((float*)o + (size_t)row * 64 + k4) = make_float4(a0, a1, a2, a3);
            }
        }
    }
}

struct GemmJobs {
    const float* x[4]; const float* WT[4]; const float* b[4]; void* o[4];
    int n[4]; int tend[4]; int half_out[4];
};

__global__ __launch_bounds__(256) void k_gemm_all(GemmJobs J) {
    int lane = threadIdx.x & 63;
    int gtile = (blockIdx.x * blockDim.x + threadIdx.x) >> 6;
    if (gtile >= J.tend[3]) return;
    const float* x; const float* WT; const float* b; void* o; int n; int base; int ho;
    if (gtile < J.tend[0]) { x = J.x[0]; WT = J.WT[0]; b = J.b[0]; o = J.o[0]; n = J.n[0]; base = 0; ho = J.half_out[0]; }
    else if (gtile < J.tend[1]) { x = J.x[1]; WT = J.WT[1]; b = J.b[1]; o = J.o[1]; n = J.n[1]; base = J.tend[0]; ho = J.half_out[1]; }
    else if (gtile < J.tend[2]) { x = J.x[2]; WT = J.WT[2]; b = J.b[2]; o = J.o[2]; n = J.n[2]; base = J.tend[1]; ho = J.half_out[2]; }
    else { x = J.x[3]; WT = J.WT[3]; b = J.b[3]; o = J.o[3]; n = J.n[3]; base = J.tend[2]; ho = J.half_out[3]; }
    int row = (gtile - base) * 64 + lane;
    bool valid = row < n;
    int rr = valid ? row : 0;
    float xr[64];
    const float4* xp = (const float4*)(x + (size_t)rr * 64);
#pragma unroll
    for (int i = 0; i < 16; ++i) {
        float4 v = xp[i];
        xr[4 * i + 0] = v.x; xr[4 * i + 1] = v.y; xr[4 * i + 2] = v.z; xr[4 * i + 3] = v.w;
    }
    gemm_one(xr, row, valid, WT, b, o, ho);
}

// ================= GATv2 building blocks =================

template <int CTRL>
__device__ __forceinline__ float dppadd_(float x) {
    int y = __builtin_amdgcn_update_dpp(0, __float_as_int(x), CTRL, 0xF, 0xF, true);
    return x + __int_as_float(y);
}

// sum across each aligned 16-lane group (all lanes get the total); VALU-only
__device__ __forceinline__ float red16_(float c) {
    c = dppadd_<0xB1>(c);   // quad_perm xor1
    c = dppadd_<0x4E>(c);   // quad_perm xor2
    c = dppadd_<0x124>(c);  // row_ror:4
    c = dppadd_<0x128>(c);  // row_ror:8
    return c;
}

template <int HAS_EF>
__device__ __forceinline__ unsigned boff_(unsigned pr) {
    return HAS_EF ? ((pr & 0xFFFFu) << 7) : pr;  // pp payloads pre-shifted
}

// Edge loop over fp16 rows; message/dot math in packed half2 (v_pk_* + v_dot2).
// No max-subtraction (scores O(+-5): fp32 exp safe). att pre-scaled by log2(e)
// and pre-converted to f16x2. slot = lane>>4 (4 edges in flight), g = lane&15.
// Payload arrays are zero-padded 16 entries -> no clamping anywhere.
template <int HAS_EF>
__device__ __forceinline__ void gat_pass(
    const void* __restrict__ hl, const unsigned* __restrict__ pay,
    int beg, int end, int slot, int g,
    f16x2 hr01, f16x2 hr23, f16x2 att01, f16x2 att23,
    f16x2 we01, f16x2 we23,
    float& s_run, float4& acc) {
    s_run = 0.f;
    acc = make_float4(0.f, 0.f, 0.f, 0.f);
    if (beg >= end) return;
    unsigned goff = (unsigned)g * 8u;
    int p = beg + slot;
    unsigned pr0 = pay[p], pr1 = pay[p + 4], pr2 = pay[p + 8], pr3;
    uint2 u0 = ld8_(hl, boff_<HAS_EF>(pr0) + goff);
    uint2 u1 = ld8_(hl, boff_<HAS_EF>(pr1) + goff);
    int pend = end + slot;
    for (; p < pend; p += 4) {
        pr3 = pay[p + 12];
        uint2 u2 = ld8_(hl, boff_<HAS_EF>(pr2) + goff);
        f16x2 m01 = *(f16x2*)&u0.x + hr01;
        f16x2 m23 = *(f16x2*)&u0.y + hr23;
        if (HAS_EF) {
            unsigned uh = pr0 & 0xFFFF0000u;
            unsigned lbu = uh | (uh >> 16);
            f16x2 lb2 = *(f16x2*)&lbu;
            m01 = lb2 * we01 + m01;   // v_pk_fma_f16
            m23 = lb2 * we23 + m23;
        }
        m01 = __builtin_elementwise_max(m01, m01 * (_Float16)0.2f);  // leaky(0.2)
        m23 = __builtin_elementwise_max(m23, m23 * (_Float16)0.2f);
        float c = fdot2_(m01, att01, 0.f);
        c = fdot2_(m23, att23, c);
        c = red16_(c);
        float w = (p < end) ? exp2f(c) : 0.f;
        s_run += w;
        float4 h = unpk_(u0);
        acc.x = fmaf(w, h.x, acc.x);
        acc.y = fmaf(w, h.y, acc.y);
        acc.z = fmaf(w, h.z, acc.z);
        acc.w = fmaf(w, h.w, acc.w);
        pr0 = pr1; pr1 = pr2; pr2 = pr3; u0 = u1; u1 = u2;
    }
}

// cross-slot totals: pure butterfly adds
__device__ __forceinline__ void slot_merge(float& s, float4& a) {
#pragma unroll
    for (int mask = 16; mask <= 32; mask <<= 1) {
        s += __shfl_xor(s, mask, 64);
        a.x += __shfl_xor(a.x, mask, 64);
        a.y += __shfl_xor(a.y, mask, 64);
        a.z += __shfl_xor(a.z, mask, 64);
        a.w += __shfl_xor(a.w, mask, 64);
    }
}

__device__ __forceinline__ void finish_row(float s_run, float4 a,
                                           const float* __restrict__ bias, int g,
                                           float o4[4]) {
    float inv = 1.f / (s_run + 1e-16f);
    float4 b4 = *(const float4*)(bias + g * 4);
    o4[0] = fmaxf(fmaf(a.x, inv, b4.x), 0.f);
    o4[1] = fmaxf(fmaf(a.y, inv, b4.y), 0.f);
    o4[2] = fmaxf(fmaf(a.z, inv, b4.z), 0.f);
    o4[3] = fmaxf(fmaf(a.w, inv, b4.w), 0.f);
}

// In-wave GEMV row@W via LDS row broadcast: slot0 writes the 64-float row,
// each lane reads its slot's 16 j values (4x ds_read_b128), 64 fma, cross-slot
// butterfly. Same-wave LDS RAW: DS ops are in-order per wave; fences stop
// compiler reordering.
__device__ __forceinline__ float4 gemv64(const float o4[4], float* __restrict__ lds_row,
                                         int slot, int g, const float* __restrict__ W) {
    if (slot == 0) *(float4*)(lds_row + 4 * g) = make_float4(o4[0], o4[1], o4[2], o4[3]);
    __asm__ volatile("" ::: "memory");
    __builtin_amdgcn_wave_barrier();
    float4 r0 = *(const float4*)(lds_row + slot * 16 + 0);
    float4 r1 = *(const float4*)(lds_row + slot * 16 + 4);
    float4 r2 = *(const float4*)(lds_row + slot * 16 + 8);
    float4 r3 = *(const float4*)(lds_row + slot * 16 + 12);
    __asm__ volatile("" ::: "memory");
    __builtin_amdgcn_wave_barrier();
    float rv[16] = {r0.x, r0.y, r0.z, r0.w, r1.x, r1.y, r1.z, r1.w,
                    r2.x, r2.y, r2.z, r2.w, r3.x, r3.y, r3.z, r3.w};
    const float* Wp = W + slot * 16 * 64 + g * 4;
    float a0 = 0.f, a1 = 0.f, a2 = 0.f, a3 = 0.f;
#pragma unroll
    for (int t = 0; t < 16; ++t) {
        float4 w4 = *(const float4*)(Wp + t * 64);
        a0 = fmaf(rv[t], w4.x, a0); a1 = fmaf(rv[t], w4.y, a1);
        a2 = fmaf(rv[t], w4.z, a2); a3 = fmaf(rv[t], w4.w, a3);
    }
    a0 += __shfl_xor(a0, 16, 64); a0 += __shfl_xor(a0, 32, 64);
    a1 += __shfl_xor(a1, 16, 64); a1 += __shfl_xor(a1, 32, 64);
    a2 += __shfl_xor(a2, 16, 64); a2 += __shfl_xor(a2, 32, 64);
    a3 += __shfl_xor(a3, 16, 64); a3 += __shfl_xor(a3, 32, 64);
    return make_float4(a0, a1, a2, a3);
}

// conv1 (products): GAT + relu + @W3l + b3l -> hl3 (fp16)
__global__ __launch_bounds__(256) void k_gat1(
    const void* __restrict__ hl, const float* __restrict__ hr,
    const int* __restrict__ offs, const unsigned* __restrict__ esrc,
    const float* __restrict__ att, const float* __restrict__ bias,
    const float* __restrict__ W2, const float* __restrict__ b2,
    void* __restrict__ out2, int ndst) {
    __shared__ float rowbuf[4][64];
    int wid = (blockIdx.x * blockDim.x + threadIdx.x) >> 6;
    if (wid >= ndst) return;
    int lane = threadIdx.x & 63, slot = lane >> 4, g = lane & 15;
    float* lrow = rowbuf[threadIdx.x >> 6];
    float4 hrf = *(const float4*)(hr + (size_t)wid * 64 + g * 4);
    f16x2 hr01 = pkc_(hrf.x, hrf.y), hr23 = pkc_(hrf.z, hrf.w);
    float4 at = *(const float4*)(att + g * 4);
    const float L2E = 1.44269504f;
    f16x2 att01 = pkc_(at.x * L2E, at.y * L2E), att23 = pkc_(at.z * L2E, at.w * L2E);
    int beg = offs[wid], end = offs[wid + 1];
    float s; float4 a;
    gat_pass<0>(hl, esrc, beg, end, slot, g, hr01, hr23, att01, att23, att01, att23, s, a);
    slot_merge(s, a);
    float o4[4];
    finish_row(s, a, bias, g, o4);
    float4 o = gemv64(o4, lrow, slot, g, W2);
    float4 bb = *(const float4*)(b2 + g * 4);
    o.x += bb.x; o.y += bb.y; o.z += bb.z; o.w += bb.w;
    if (slot == 0)
        *(uint2*)((char*)out2 + (size_t)wid * 128 + g * 8) =
            make_uint2(pkh_(o.x, o.y), pkh_(o.z, o.w));
}

// conv2 + conv3 fused per customer node
__global__ __launch_bounds__(256) void k_gat23(
    const void* __restrict__ hl2, const float* __restrict__ hr2,
    const void* __restrict__ hl3,
    const int* __restrict__ offs, const unsigned* __restrict__ epay,
    const float* __restrict__ We2, const float* __restrict__ att2, const float* __restrict__ bias2,
    const float* __restrict__ W3r, const float* __restrict__ b3r,
    const float* __restrict__ We3, const float* __restrict__ att3, const float* __restrict__ bias3,
    const float* __restrict__ Wlin, const float* __restrict__ blin,
    float* __restrict__ outp, int ndst) {
    __shared__ float rowbuf[4][64];
    int wid = (blockIdx.x * blockDim.x + threadIdx.x) >> 6;
    if (wid >= ndst) return;
    int lane = threadIdx.x & 63, slot = lane >> 4, g = lane & 15;
    float* lrow = rowbuf[threadIdx.x >> 6];
    int beg = offs[wid], end = offs[wid + 1];
    const float L2E = 1.44269504f;
    // ---- conv2 ----
    float4 hrf = *(const float4*)(hr2 + (size_t)wid * 64 + g * 4);
    f16x2 hr01 = pkc_(hrf.x, hrf.y), hr23 = pkc_(hrf.z, hrf.w);
    float4 at = *(const float4*)(att2 + g * 4);
    f16x2 att01 = pkc_(at.x * L2E, at.y * L2E), att23 = pkc_(at.z * L2E, at.w * L2E);
    float4 wef = *(const float4*)(We2 + g * 4);
    f16x2 we01 = pkc_(wef.x, wef.y), we23 = pkc_(wef.z, wef.w);
    float s; float4 a;
    gat_pass<1>(hl2, epay, beg, end, slot, g, hr01, hr23, att01, att23, we01, we23, s, a);
    slot_merge(s, a);
    float o4[4];
    finish_row(s, a, bias2, g, o4);
    float4 h3 = gemv64(o4, lrow, slot, g, W3r);
    float4 bb = *(const float4*)(b3r + g * 4);
    h3.x += bb.x; h3.y += bb.y; h3.z += bb.z; h3.w += bb.w;
    // ---- conv3 ----
    hr01 = pkc_(h3.x, h3.y); hr23 = pkc_(h3.z, h3.w);
    at = *(const float4*)(att3 + g * 4);
    att01 = pkc_(at.x * L2E, at.y * L2E); att23 = pkc_(at.z * L2E, at.w * L2E);
    wef = *(const float4*)(We3 + g * 4);
    we01 = pkc_(wef.x, wef.y); we23 = pkc_(wef.z, wef.w);
    gat_pass<1>(hl3, epay, beg, end, slot, g, hr01, hr23, att01, att23, we01, we23, s, a);
    slot_merge(s, a);
    finish_row(s, a, bias3, g, o4);
    float4 o = gemv64(o4, lrow, slot, g, Wlin);
    float4 bl = *(const float4*)(blin + g * 4);
    o.x += bl.x; o.y += bl.y; o.z += bl.z; o.w += bl.w;
    if (slot == 0) *(float4*)(outp + (size_t)wid * 64 + g * 4) = o;
}

// ================= launch =================

extern "C" void kernel_launch(void* const* d_in, const int* in_sizes, int n_in,
                              void* d_out, int out_size, void* d_ws, size_t ws_size,
                              hipStream_t stream) {
    const float* x_p = (const float*)d_in[0];
    const float* x_c = (const float*)d_in[1];
    const float* elab_in = (const float*)d_in[2];
    const int* src_pp = (const int*)d_in[3];
    const int* dst_pp = (const int*)d_in[4];
    const int* src_pc = (const int*)d_in[5];
    const int* dst_pc = (const int*)d_in[6];
    const float* W1l = (const float*)d_in[7];
    const float* b1l = (const float*)d_in[8];
    const float* W1r = (const float*)d_in[9];
    const float* b1r = (const float*)d_in[10];
    const float* att1 = (const float*)d_in[11];
    const float* bias1 = (const float*)d_in[12];
    const float* W2l = (const float*)d_in[13];
    const float* b2l = (const float*)d_in[14];
    const float* W2r = (const float*)d_in[15];
    const float* b2r = (const float*)d_in[16];
    const float* We2 = (const float*)d_in[17];
    const float* att2 = (const float*)d_in[18];
    const float* bias2 = (const float*)d_in[19];
    const float* W3l = (const float*)d_in[20];
    const float* b3l = (const float*)d_in[21];
    const float* W3r = (const float*)d_in[22];
    const float* b3r = (const float*)d_in[23];
    const float* We3 = (const float*)d_in[24];
    const float* att3 = (const float*)d_in[25];
    const float* bias3 = (const float*)d_in[26];
    const float* Wlin = (const float*)d_in[27];
    const float* blin = (const float*)d_in[28];
    float* out = (float*)d_out;

    const int NP = in_sizes[0] / 64;
    const int NC = in_sizes[1] / 64;
    const int EPP = in_sizes[3];
    const int EPC = in_sizes[5];
    const int E1 = EPP + NP;

    // workspace layout (256B-aligned chunks)
    char* w = (char*)d_ws;
    auto alloc = [&](size_t bytes) { char* r = w; w += (bytes + 255) & ~(size_t)255; return r; };
    void* hl1 = alloc((size_t)NP * 128);       // fp16
    void* hl2 = alloc((size_t)NP * 128);       // fp16
    void* hl3 = alloc((size_t)NP * 128);       // fp16 (conv1-fused output)
    float* hr1 = (float*)alloc((size_t)NP * 256);
    float* hr2 = (float*)alloc((size_t)NC * 256);
    float* wt = (float*)alloc(4 * 4096 * 4);
    unsigned* epay = (unsigned*)alloc((size_t)(EPC + 16) * 4);
    unsigned* e1src = (unsigned*)alloc((size_t)(E1 + 16) * 4);
    int* off1 = (int*)alloc((size_t)(NP + 1) * 4);
    int* cnt1 = (int*)alloc((size_t)NP * 4);
    int* off2 = (int*)alloc((size_t)(NC + 1) * 4);
    int* cnt2 = (int*)alloc((size_t)NC * 4);
    int* incl1 = (int*)alloc((size_t)NP * 4);
    int* incl2 = (int*)alloc((size_t)NC * 4);
    int* bsum1 = (int*)alloc(1024 * 4);
    int* bsum2 = (int*)alloc(1024 * 4);

    int nb1 = ceil_div(NP, 1024), nb2 = ceil_div(NC, 1024);
    int maxE = EPC > EPP ? EPC : EPP; if (NP > maxE) maxE = NP;
    int maxN = NC > NP ? NC : NP;

    (void)hipMemsetAsync(cnt1, 0, (size_t)NP * 4, stream);
    (void)hipMemsetAsync(cnt2, 0, (size_t)NC * 4, stream);

    k_transpose_all<<<dim3(64, 4), 64, 0, stream>>>(W1l, W1r, W2l, W2r, wt);

    k_count_all<<<ceil_div(maxE, 256), 256, 0, stream>>>(NP, dst_pp, EPP, dst_pc, EPC, cnt1, cnt2);
    k_scan1<<<dim3(nb2 > nb1 ? nb2 : nb1, 2), 1024, 0, stream>>>(
        cnt1, NP, incl1, bsum1, cnt2, NC, incl2, bsum2);
    k_scan2<<<dim3(1, 2), 1024, 0, stream>>>(bsum1, nb1, bsum2, nb2);
    k_scan3<<<dim3(ceil_div(maxN, 256), 2), 256, 0, stream>>>(
        cnt1, incl1, bsum1, NP, off1, cnt1, cnt2, incl2, bsum2, NC, off2, cnt2);
    k_scatter_all<<<ceil_div(maxE, 256), 256, 0, stream>>>(
        NP, src_pp, dst_pp, EPP, src_pc, dst_pc, elab_in, EPC, E1, cnt1, cnt2, e1src, epay);

    // fused input transforms: hl1 = x_p@W1l (h), hr1 = x_p@W1r (f), hl2 = x_p@W2l (h), hr2 = x_c@W2r (f)
    int tp = ceil_div(NP, 64), tc = ceil_div(NC, 64);
    GemmJobs J;
    J.x[0] = x_p; J.WT[0] = wt + 0 * 4096; J.b[0] = b1l; J.o[0] = hl1; J.n[0] = NP; J.half_out[0] = 1;
    J.x[1] = x_p; J.WT[1] = wt + 1 * 4096; J.b[1] = b1r; J.o[1] = hr1; J.n[1] = NP; J.half_out[1] = 0;
    J.x[2] = x_p; J.WT[2] = wt + 2 * 4096; J.b[2] = b2l; J.o[2] = hl2; J.n[2] = NP; J.half_out[2] = 1;
    J.x[3] = x_c; J.WT[3] = wt + 3 * 4096; J.b[3] = b2r; J.o[3] = hr2; J.n[3] = NC; J.half_out[3] = 0;
    J.tend[0] = tp; J.tend[1] = 2 * tp; J.tend[2] = 3 * tp; J.tend[3] = 3 * tp + tc;
    k_gemm_all<<<ceil_div(J.tend[3] * 64, 256), 256, 0, stream>>>(J);

    // conv1 -> (relu -> @W3l + b3l) -> hl3 (fp16)
    k_gat1<<<ceil_div(NP * 64, 256), 256, 0, stream>>>(
        hl1, hr1, off1, e1src, att1, bias1, W3l, b3l, hl3, NP);

    // conv2+conv3 fused -> d_out
    k_gat23<<<ceil_div(NC * 64, 256), 256, 0, stream>>>(
        hl2, hr2, hl3, off2, epay, We2, att2, bias2, W3r, b3r,
        We3, att3, bias3, Wlin, blin, out, NC);
}

// Round 10
// 590.451 us; speedup vs baseline: 3.5032x; 1.1529x over previous
//
#include <hip/hip_runtime.h>
#include <hip/hip_fp16.h>

static inline int ceil_div(int a, int b) { return (a + b - 1) / b; }

typedef _Float16 f16x2 __attribute__((ext_vector_type(2)));

#define PART_CHUNK 8192

// ================= CSR build =================

__global__ void k_count_all(int NP, const int* __restrict__ dst_pp, int EPP,
                            const int* __restrict__ dst_pc, int EPC,
                            int* __restrict__ cnt1, int* __restrict__ cnt2) {
    int e = blockIdx.x * blockDim.x + threadIdx.x;
    if (e < NP) atomicAdd(&cnt1[e], 1);  // self loop
    if (e < EPP) atomicAdd(&cnt1[dst_pp[e]], 1);
    if (e < EPC) atomicAdd(&cnt2[dst_pc[e]], 1);
}

__global__ void k_scan1(const int* c1, int n1, int* i1, int* bs1,
                        const int* c2, int n2, int* i2, int* bs2) {
    const int* cnt = blockIdx.y ? c2 : c1;
    int n = blockIdx.y ? n2 : n1;
    int* incl = blockIdx.y ? i2 : i1;
    int* bsum = blockIdx.y ? bs2 : bs1;
    if ((int)blockIdx.x * 1024 >= n) return;
    __shared__ int sm[1024];
    int tid = threadIdx.x;
    int i = blockIdx.x * 1024 + tid;
    sm[tid] = (i < n) ? cnt[i] : 0;
    __syncthreads();
    for (int off = 1; off < 1024; off <<= 1) {
        int t = (tid >= off) ? sm[tid - off] : 0;
        __syncthreads();
        sm[tid] += t;
        __syncthreads();
    }
    if (i < n) incl[i] = sm[tid];
    if (tid == 1023) bsum[blockIdx.x] = sm[1023];
}

__global__ void k_scan2(int* bs1, int nb1, int* bs2, int nb2) {
    int* bsum = blockIdx.y ? bs2 : bs1;
    int nb = blockIdx.y ? nb2 : nb1;
    __shared__ int sm[1024];
    int tid = threadIdx.x;
    sm[tid] = (tid < nb) ? bsum[tid] : 0;
    __syncthreads();
    for (int off = 1; off < 1024; off <<= 1) {
        int t = (tid >= off) ? sm[tid - off] : 0;
        __syncthreads();
        sm[tid] += t;
        __syncthreads();
    }
    if (tid < nb) bsum[tid] = sm[tid];
}

// also initializes per-bucket staging cursors bcur[b] = offs[b*512]
__global__ void k_scan3(const int* c1, const int* i1, const int* bs1, int n1, int* o1, int* u1, int* bc1,
                        const int* c2, const int* i2, const int* bs2, int n2, int* o2, int* u2, int* bc2) {
    const int* cnt = blockIdx.y ? c2 : c1;
    const int* incl = blockIdx.y ? i2 : i1;
    const int* bsum = blockIdx.y ? bs2 : bs1;
    int n = blockIdx.y ? n2 : n1;
    int* offs = blockIdx.y ? o2 : o1;
    int* cur = blockIdx.y ? u2 : u1;
    int* bcur = blockIdx.y ? bc2 : bc1;
    int i = blockIdx.x * blockDim.x + threadIdx.x;
    if (i >= n) return;
    int b = i >> 10;
    int inc = incl[i] + (b ? bsum[b - 1] : 0);
    int off = inc - cnt[i];
    offs[i] = off;
    cur[i] = off;
    if ((i & 511) == 0) bcur[i >> 9] = off;
    if (i == n - 1) offs[n] = inc;
}

// Phase A: radix-partition edges into 512-node dst-buckets. Per-workgroup LDS
// histogram + ONE global atomicAdd per (wg,bucket) reservation (low contention,
// unlike the naive per-edge bucket-cursor scatter), then LDS-ranked scatter ->
// staging writes are ~300B contiguous runs. record: (payload, dst).
__global__ __launch_bounds__(256) void k_partA(
    int NP, const int* __restrict__ src_pp, const int* __restrict__ dst_pp, int E1,
    const int* __restrict__ src_pc, const int* __restrict__ dst_pc,
    const float* __restrict__ lab, int EPC,
    int* __restrict__ bcur1, int* __restrict__ bcur2,
    uint2* __restrict__ stg1, uint2* __restrict__ stg2) {
    __shared__ int hist[256];
    __shared__ int base[256];
    int g = blockIdx.y;   // 0 = product graph (self+pp), 1 = customer graph (pc)
    int E = g ? EPC : E1;
    int e0 = blockIdx.x * PART_CHUNK;
    if (e0 >= E) return;
    int e1 = e0 + PART_CHUNK < E ? e0 + PART_CHUNK : E;
    int tid = threadIdx.x;
    hist[tid] = 0;
    __syncthreads();
    for (int i = e0 + tid; i < e1; i += 256) {
        int d = g ? dst_pc[i] : (i < NP ? i : dst_pp[i - NP]);
        atomicAdd(&hist[d >> 9], 1);
    }
    __syncthreads();
    int h = hist[tid];
    base[tid] = h ? atomicAdd((g ? bcur2 : bcur1) + tid, h) : 0;
    hist[tid] = 0;
    __syncthreads();
    uint2* stg = g ? stg2 : stg1;
    for (int i = e0 + tid; i < e1; i += 256) {
        int d; unsigned pay;
        if (g) {
            d = dst_pc[i];
            unsigned hh = (unsigned)__half_as_ushort(__float2half_rn(lab[i]));
            pay = (unsigned)src_pc[i] | (hh << 16);
        } else {
            int s;
            if (i < NP) { d = i; s = i; } else { d = dst_pp[i - NP]; s = src_pp[i - NP]; }
            pay = (unsigned)s << 7;
        }
        int b = d >> 9;
        int r = atomicAdd(&hist[b], 1);
        stg[base[b] + r] = make_uint2(pay, (unsigned)d);
    }
}

// Phase B: one workgroup per bucket; re-scatter into final CSR slots. Random
// writes confined to the bucket's ~130KB CSR window (L2-resident). Also
// zero-pads 16 entries past each array end (clamp-free prefetch in gat).
__global__ __launch_bounds__(256) void k_partB(
    int NB1, int NP, const int* __restrict__ off1, int* __restrict__ cur1,
    const uint2* __restrict__ stg1, unsigned* __restrict__ e1src, int E1,
    int NC, const int* __restrict__ off2, int* __restrict__ cur2,
    const uint2* __restrict__ stg2, unsigned* __restrict__ epay, int EPC) {
    int b = blockIdx.x;
    if (b == 0 && threadIdx.x < 16) {
        e1src[E1 + threadIdx.x] = 0u;
        epay[EPC + threadIdx.x] = 0u;
    }
    if (b < NB1) {
        int n0 = b << 9;
        int n1 = (n0 + 512) < NP ? (n0 + 512) : NP;
        int lo = off1[n0], hi = off1[n1];
        for (int i = lo + threadIdx.x; i < hi; i += 256) {
            uint2 r = stg1[i];
            int pos = atomicAdd(&cur1[r.y], 1);
            e1src[pos] = r.x;
        }
    } else {
        int bb = b - NB1;
        int n0 = bb << 9;
        int n1 = (n0 + 512) < NC ? (n0 + 512) : NC;
        int lo = off2[n0], hi = off2[n1];
        for (int i = lo + threadIdx.x; i < hi; i += 256) {
            uint2 r = stg2[i];
            int pos = atomicAdd(&cur2[r.y], 1);
            epay[pos] = r.x;
        }
    }
}

// ================= weight transpose =================

__global__ void k_transpose_all(const float* s0, const float* s1, const float* s2,
                                const float* s3, float* __restrict__ wt) {
    const float* S[4] = {s0, s1, s2, s3};
    const float* W = S[blockIdx.y];
    int j = threadIdx.x, k = blockIdx.x;
    wt[blockIdx.y * 4096 + k * 64 + j] = W[j * 64 + k];
}

// ================= helpers =================

__device__ __forceinline__ unsigned pkh_(float a, float b) {
    __half2 h = __floats2half2_rn(a, b);
    return *(unsigned*)&h;
}

__device__ __forceinline__ f16x2 pkc_(float a, float b) {
    f16x2 r;
    r.x = (_Float16)a;
    r.y = (_Float16)b;
    return r;
}

__device__ __forceinline__ uint2 ld8_(const void* p, unsigned boff) {
    return *(const uint2*)((const char*)p + boff);
}

__device__ __forceinline__ float4 unpk_(uint2 u) {
    f16x2 h01 = *(f16x2*)&u.x, h23 = *(f16x2*)&u.y;
    return make_float4((float)h01.x, (float)h01.y, (float)h23.x, (float)h23.y);
}

__device__ __forceinline__ float fdot2_(f16x2 a, f16x2 b, float c) {
#if __has_builtin(__builtin_amdgcn_fdot2)
    return __builtin_amdgcn_fdot2(a, b, c, false);
#else
    return fmaf((float)a.x, (float)b.x, fmaf((float)a.y, (float)b.y, c));
#endif
}

// ================= fused input-transform GEMMs =================

__device__ __forceinline__ void gemm_one(const float xr[64], int row, bool valid,
                                         const float* __restrict__ WT,
                                         const float* __restrict__ b,
                                         void* __restrict__ o, int half_out) {
    for (int k4 = 0; k4 < 64; k4 += 4) {
        float a0 = b[k4 + 0], a1 = b[k4 + 1], a2 = b[k4 + 2], a3 = b[k4 + 3];
#pragma unroll
        for (int j = 0; j < 64; ++j) {
            float xv = xr[j];
            a0 = fmaf(xv, WT[(k4 + 0) * 64 + j], a0);
            a1 = fmaf(xv, WT[(k4 + 1) * 64 + j], a1);
            a2 = fmaf(xv, WT[(k4 + 2) * 64 + j], a2);
            a3 = fmaf(xv, WT[(k4 + 3) * 64 + j], a3);
        }
        if (valid) {
            if (half_out) {
                *(uint2*)((char*)o + (size_t)row * 128 + k4 * 2) =
                    make_uint2(pkh_(a0, a1), pkh_(a2, a3));
            } else {
                *(float4*)((float*)o + (size_t)row * 64 + k4) = make_float4(a0, a1, a2, a3);
            }
        }
    }
}

struct GemmJobs {
    const float* x[4]; const float* WT[4]; const float* b[4]; void* o[4];
    int n[4]; int tend[4]; int half_out[4];
};

__global__ __launch_bounds__(256) void k_gemm_all(GemmJobs J) {
    int lane = threadIdx.x & 63;
    int gtile = (blockIdx.x * blockDim.x + threadIdx.x) >> 6;
    if (gtile >= J.tend[3]) return;
    const float* x; const float* WT; const float* b; void* o; int n; int base; int ho;
    if (gtile < J.tend[0]) { x = J.x[0]; WT = J.WT[0]; b = J.b[0]; o = J.o[0]; n = J.n[0]; base = 0; ho = J.half_out[0]; }
    else if (gtile < J.tend[1]) { x = J.x[1]; WT = J.WT[1]; b = J.b[1]; o = J.o[1]; n = J.n[1]; base = J.tend[0]; ho = J.half_out[1]; }
    else if (gtile < J.tend[2]) { x = J.x[2]; WT = J.WT[2]; b = J.b[2]; o = J.o[2]; n = J.n[2]; base = J.tend[1]; ho = J.half_out[2]; }
    else { x = J.x[3]; WT = J.WT[3]; b = J.b[3]; o = J.o[3]; n = J.n[3]; base = J.tend[2]; ho = J.half_out[3]; }
    int row = (gtile - base) * 64 + lane;
    bool valid = row < n;
    int rr = valid ? row : 0;
    float xr[64];
    const float4* xp = (const float4*)(x + (size_t)rr * 64);
#pragma unroll
    for (int i = 0; i < 16; ++i) {
        float4 v = xp[i];
        xr[4 * i + 0] = v.x; xr[4 * i + 1] = v.y; xr[4 * i + 2] = v.z; xr[4 * i + 3] = v.w;
    }
    gemm_one(xr, row, valid, WT, b, o, ho);
}

// ================= GATv2 building blocks =================

template <int CTRL>
__device__ __forceinline__ float dppadd_(float x) {
    int y = __builtin_amdgcn_update_dpp(0, __float_as_int(x), CTRL, 0xF, 0xF, true);
    return x + __int_as_float(y);
}

// sum across each aligned 16-lane group (all lanes get the total); VALU-only
__device__ __forceinline__ float red16_(float c) {
    c = dppadd_<0xB1>(c);   // quad_perm xor1
    c = dppadd_<0x4E>(c);   // quad_perm xor2
    c = dppadd_<0x124>(c);  // row_ror:4
    c = dppadd_<0x128>(c);  // row_ror:8
    return c;
}

template <int HAS_EF>
__device__ __forceinline__ unsigned boff_(unsigned pr) {
    return HAS_EF ? ((pr & 0xFFFFu) << 7) : pr;  // pp payloads pre-shifted
}

// Edge loop over fp16 rows; message/dot math in packed half2 (v_pk_* + v_dot2).
// No max-subtraction (scores O(+-5): fp32 exp safe). att pre-scaled by log2(e)
// and pre-converted to f16x2. slot = lane>>4 (4 edges in flight), g = lane&15.
// Payload arrays are zero-padded 16 entries -> no clamping anywhere.
template <int HAS_EF>
__device__ __forceinline__ void gat_pass(
    const void* __restrict__ hl, const unsigned* __restrict__ pay,
    int beg, int end, int slot, int g,
    f16x2 hr01, f16x2 hr23, f16x2 att01, f16x2 att23,
    f16x2 we01, f16x2 we23,
    float& s_run, float4& acc) {
    s_run = 0.f;
    acc = make_float4(0.f, 0.f, 0.f, 0.f);
    if (beg >= end) return;
    unsigned goff = (unsigned)g * 8u;
    int p = beg + slot;
    unsigned pr0 = pay[p], pr1 = pay[p + 4], pr2 = pay[p + 8], pr3;
    uint2 u0 = ld8_(hl, boff_<HAS_EF>(pr0) + goff);
    uint2 u1 = ld8_(hl, boff_<HAS_EF>(pr1) + goff);
    int pend = end + slot;
    for (; p < pend; p += 4) {
        pr3 = pay[p + 12];
        uint2 u2 = ld8_(hl, boff_<HAS_EF>(pr2) + goff);
        f16x2 m01 = *(f16x2*)&u0.x + hr01;
        f16x2 m23 = *(f16x2*)&u0.y + hr23;
        if (HAS_EF) {
            unsigned uh = pr0 & 0xFFFF0000u;
            unsigned lbu = uh | (uh >> 16);
            f16x2 lb2 = *(f16x2*)&lbu;
            m01 = lb2 * we01 + m01;   // v_pk_fma_f16
            m23 = lb2 * we23 + m23;
        }
        m01 = __builtin_elementwise_max(m01, m01 * (_Float16)0.2f);  // leaky(0.2)
        m23 = __builtin_elementwise_max(m23, m23 * (_Float16)0.2f);
        float c = fdot2_(m01, att01, 0.f);
        c = fdot2_(m23, att23, c);
        c = red16_(c);
        float w = (p < end) ? exp2f(c) : 0.f;
        s_run += w;
        float4 h = unpk_(u0);
        acc.x = fmaf(w, h.x, acc.x);
        acc.y = fmaf(w, h.y, acc.y);
        acc.z = fmaf(w, h.z, acc.z);
        acc.w = fmaf(w, h.w, acc.w);
        pr0 = pr1; pr1 = pr2; pr2 = pr3; u0 = u1; u1 = u2;
    }
}

// cross-slot totals: pure butterfly adds
__device__ __forceinline__ void slot_merge(float& s, float4& a) {
#pragma unroll
    for (int mask = 16; mask <= 32; mask <<= 1) {
        s += __shfl_xor(s, mask, 64);
        a.x += __shfl_xor(a.x, mask, 64);
        a.y += __shfl_xor(a.y, mask, 64);
        a.z += __shfl_xor(a.z, mask, 64);
        a.w += __shfl_xor(a.w, mask, 64);
    }
}

__device__ __forceinline__ void finish_row(float s_run, float4 a,
                                           const float* __restrict__ bias, int g,
                                           float o4[4]) {
    float inv = 1.f / (s_run + 1e-16f);
    float4 b4 = *(const float4*)(bias + g * 4);
    o4[0] = fmaxf(fmaf(a.x, inv, b4.x), 0.f);
    o4[1] = fmaxf(fmaf(a.y, inv, b4.y), 0.f);
    o4[2] = fmaxf(fmaf(a.z, inv, b4.z), 0.f);
    o4[3] = fmaxf(fmaf(a.w, inv, b4.w), 0.f);
}

// In-wave GEMV row@W via LDS row broadcast: slot0 writes the 64-float row,
// each lane reads its slot's 16 j values (4x ds_read_b128), 64 fma, cross-slot
// butterfly. Same-wave LDS RAW: DS ops are in-order per wave; fences stop
// compiler reordering.
__device__ __forceinline__ float4 gemv64(const float o4[4], float* __restrict__ lds_row,
                                         int slot, int g, const float* __restrict__ W) {
    if (slot == 0) *(float4*)(lds_row + 4 * g) = make_float4(o4[0], o4[1], o4[2], o4[3]);
    __asm__ volatile("" ::: "memory");
    __builtin_amdgcn_wave_barrier();
    float4 r0 = *(const float4*)(lds_row + slot * 16 + 0);
    float4 r1 = *(const float4*)(lds_row + slot * 16 + 4);
    float4 r2 = *(const float4*)(lds_row + slot * 16 + 8);
    float4 r3 = *(const float4*)(lds_row + slot * 16 + 12);
    __asm__ volatile("" ::: "memory");
    __builtin_amdgcn_wave_barrier();
    float rv[16] = {r0.x, r0.y, r0.z, r0.w, r1.x, r1.y, r1.z, r1.w,
                    r2.x, r2.y, r2.z, r2.w, r3.x, r3.y, r3.z, r3.w};
    const float* Wp = W + slot * 16 * 64 + g * 4;
    float a0 = 0.f, a1 = 0.f, a2 = 0.f, a3 = 0.f;
#pragma unroll
    for (int t = 0; t < 16; ++t) {
        float4 w4 = *(const float4*)(Wp + t * 64);
        a0 = fmaf(rv[t], w4.x, a0); a1 = fmaf(rv[t], w4.y, a1);
        a2 = fmaf(rv[t], w4.z, a2); a3 = fmaf(rv[t], w4.w, a3);
    }
    a0 += __shfl_xor(a0, 16, 64); a0 += __shfl_xor(a0, 32, 64);
    a1 += __shfl_xor(a1, 16, 64); a1 += __shfl_xor(a1, 32, 64);
    a2 += __shfl_xor(a2, 16, 64); a2 += __shfl_xor(a2, 32, 64);
    a3 += __shfl_xor(a3, 16, 64); a3 += __shfl_xor(a3, 32, 64);
    return make_float4(a0, a1, a2, a3);
}

// conv1 (products): GAT + relu + @W3l + b3l -> hl3 (fp16)
__global__ __launch_bounds__(256) void k_gat1(
    const void* __restrict__ hl, const float* __restrict__ hr,
    const int* __restrict__ offs, const unsigned* __restrict__ esrc,
    const float* __restrict__ att, const float* __restrict__ bias,
    const float* __restrict__ W2, const float* __restrict__ b2,
    void* __restrict__ out2, int ndst) {
    __shared__ float rowbuf[4][64];
    int wid = (blockIdx.x * blockDim.x + threadIdx.x) >> 6;
    if (wid >= ndst) return;
    int lane = threadIdx.x & 63, slot = lane >> 4, g = lane & 15;
    float* lrow = rowbuf[threadIdx.x >> 6];
    float4 hrf = *(const float4*)(hr + (size_t)wid * 64 + g * 4);
    f16x2 hr01 = pkc_(hrf.x, hrf.y), hr23 = pkc_(hrf.z, hrf.w);
    float4 at = *(const float4*)(att + g * 4);
    const float L2E = 1.44269504f;
    f16x2 att01 = pkc_(at.x * L2E, at.y * L2E), att23 = pkc_(at.z * L2E, at.w * L2E);
    int beg = offs[wid], end = offs[wid + 1];
    float s; float4 a;
    gat_pass<0>(hl, esrc, beg, end, slot, g, hr01, hr23, att01, att23, att01, att23, s, a);
    slot_merge(s, a);
    float o4[4];
    finish_row(s, a, bias, g, o4);
    float4 o = gemv64(o4, lrow, slot, g, W2);
    float4 bb = *(const float4*)(b2 + g * 4);
    o.x += bb.x; o.y += bb.y; o.z += bb.z; o.w += bb.w;
    if (slot == 0)
        *(uint2*)((char*)out2 + (size_t)wid * 128 + g * 8) =
            make_uint2(pkh_(o.x, o.y), pkh_(o.z, o.w));
}

// conv2 + conv3 fused per customer node
__global__ __launch_bounds__(256) void k_gat23(
    const void* __restrict__ hl2, const float* __restrict__ hr2,
    const void* __restrict__ hl3,
    const int* __restrict__ offs, const unsigned* __restrict__ epay,
    const float* __restrict__ We2, const float* __restrict__ att2, const float* __restrict__ bias2,
    const float* __restrict__ W3r, const float* __restrict__ b3r,
    const float* __restrict__ We3, const float* __restrict__ att3, const float* __restrict__ bias3,
    const float* __restrict__ Wlin, const float* __restrict__ blin,
    float* __restrict__ outp, int ndst) {
    __shared__ float rowbuf[4][64];
    int wid = (blockIdx.x * blockDim.x + threadIdx.x) >> 6;
    if (wid >= ndst) return;
    int lane = threadIdx.x & 63, slot = lane >> 4, g = lane & 15;
    float* lrow = rowbuf[threadIdx.x >> 6];
    int beg = offs[wid], end = offs[wid + 1];
    const float L2E = 1.44269504f;
    // ---- conv2 ----
    float4 hrf = *(const float4*)(hr2 + (size_t)wid * 64 + g * 4);
    f16x2 hr01 = pkc_(hrf.x, hrf.y), hr23 = pkc_(hrf.z, hrf.w);
    float4 at = *(const float4*)(att2 + g * 4);
    f16x2 att01 = pkc_(at.x * L2E, at.y * L2E), att23 = pkc_(at.z * L2E, at.w * L2E);
    float4 wef = *(const float4*)(We2 + g * 4);
    f16x2 we01 = pkc_(wef.x, wef.y), we23 = pkc_(wef.z, wef.w);
    float s; float4 a;
    gat_pass<1>(hl2, epay, beg, end, slot, g, hr01, hr23, att01, att23, we01, we23, s, a);
    slot_merge(s, a);
    float o4[4];
    finish_row(s, a, bias2, g, o4);
    float4 h3 = gemv64(o4, lrow, slot, g, W3r);
    float4 bb = *(const float4*)(b3r + g * 4);
    h3.x += bb.x; h3.y += bb.y; h3.z += bb.z; h3.w += bb.w;
    // ---- conv3 ----
    hr01 = pkc_(h3.x, h3.y); hr23 = pkc_(h3.z, h3.w);
    at = *(const float4*)(att3 + g * 4);
    att01 = pkc_(at.x * L2E, at.y * L2E); att23 = pkc_(at.z * L2E, at.w * L2E);
    wef = *(const float4*)(We3 + g * 4);
    we01 = pkc_(wef.x, wef.y); we23 = pkc_(wef.z, wef.w);
    gat_pass<1>(hl3, epay, beg, end, slot, g, hr01, hr23, att01, att23, we01, we23, s, a);
    slot_merge(s, a);
    finish_row(s, a, bias3, g, o4);
    float4 o = gemv64(o4, lrow, slot, g, Wlin);
    float4 bl = *(const float4*)(blin + g * 4);
    o.x += bl.x; o.y += bl.y; o.z += bl.z; o.w += bl.w;
    if (slot == 0) *(float4*)(outp + (size_t)wid * 64 + g * 4) = o;
}

// ================= launch =================

extern "C" void kernel_launch(void* const* d_in, const int* in_sizes, int n_in,
                              void* d_out, int out_size, void* d_ws, size_t ws_size,
                              hipStream_t stream) {
    const float* x_p = (const float*)d_in[0];
    const float* x_c = (const float*)d_in[1];
    const float* elab_in = (const float*)d_in[2];
    const int* src_pp = (const int*)d_in[3];
    const int* dst_pp = (const int*)d_in[4];
    const int* src_pc = (const int*)d_in[5];
    const int* dst_pc = (const int*)d_in[6];
    const float* W1l = (const float*)d_in[7];
    const float* b1l = (const float*)d_in[8];
    const float* W1r = (const float*)d_in[9];
    const float* b1r = (const float*)d_in[10];
    const float* att1 = (const float*)d_in[11];
    const float* bias1 = (const float*)d_in[12];
    const float* W2l = (const float*)d_in[13];
    const float* b2l = (const float*)d_in[14];
    const float* W2r = (const float*)d_in[15];
    const float* b2r = (const float*)d_in[16];
    const float* We2 = (const float*)d_in[17];
    const float* att2 = (const float*)d_in[18];
    const float* bias2 = (const float*)d_in[19];
    const float* W3l = (const float*)d_in[20];
    const float* b3l = (const float*)d_in[21];
    const float* W3r = (const float*)d_in[22];
    const float* b3r = (const float*)d_in[23];
    const float* We3 = (const float*)d_in[24];
    const float* att3 = (const float*)d_in[25];
    const float* bias3 = (const float*)d_in[26];
    const float* Wlin = (const float*)d_in[27];
    const float* blin = (const float*)d_in[28];
    float* out = (float*)d_out;

    const int NP = in_sizes[0] / 64;
    const int NC = in_sizes[1] / 64;
    const int EPP = in_sizes[3];
    const int EPC = in_sizes[5];
    const int E1 = EPP + NP;
    const int NB1 = ceil_div(NP, 512), NB2 = ceil_div(NC, 512);

    // workspace layout (256B-aligned chunks)
    char* w = (char*)d_ws;
    auto alloc = [&](size_t bytes) { char* r = w; w += (bytes + 255) & ~(size_t)255; return r; };
    void* hl1 = alloc((size_t)NP * 128);       // fp16
    void* hl2 = alloc((size_t)NP * 128);       // fp16
    void* hl3 = alloc((size_t)NP * 128);       // fp16 (conv1-fused output)
    float* hr1 = (float*)alloc((size_t)NP * 256);
    float* hr2 = (float*)alloc((size_t)NC * 256);
    float* wt = (float*)alloc(4 * 4096 * 4);
    unsigned* epay = (unsigned*)alloc((size_t)(EPC + 16) * 4);
    unsigned* e1src = (unsigned*)alloc((size_t)(E1 + 16) * 4);
    uint2* stg1 = (uint2*)alloc((size_t)E1 * 8);
    uint2* stg2 = (uint2*)alloc((size_t)EPC * 8);
    int* off1 = (int*)alloc((size_t)(NP + 1) * 4);
    int* cnt1 = (int*)alloc((size_t)NP * 4);
    int* off2 = (int*)alloc((size_t)(NC + 1) * 4);
    int* cnt2 = (int*)alloc((size_t)NC * 4);
    int* incl1 = (int*)alloc((size_t)NP * 4);
    int* incl2 = (int*)alloc((size_t)NC * 4);
    int* bsum1 = (int*)alloc(1024 * 4);
    int* bsum2 = (int*)alloc(1024 * 4);
    int* bcur1 = (int*)alloc(256 * 4);
    int* bcur2 = (int*)alloc(256 * 4);

    int nb1 = ceil_div(NP, 1024), nb2 = ceil_div(NC, 1024);
    int maxE = EPC > EPP ? EPC : EPP; if (NP > maxE) maxE = NP;
    int maxN = NC > NP ? NC : NP;
    int maxEp = EPC > E1 ? EPC : E1;

    (void)hipMemsetAsync(cnt1, 0, (size_t)NP * 4, stream);
    (void)hipMemsetAsync(cnt2, 0, (size_t)NC * 4, stream);

    k_transpose_all<<<dim3(64, 4), 64, 0, stream>>>(W1l, W1r, W2l, W2r, wt);

    k_count_all<<<ceil_div(maxE, 256), 256, 0, stream>>>(NP, dst_pp, EPP, dst_pc, EPC, cnt1, cnt2);
    k_scan1<<<dim3(nb2 > nb1 ? nb2 : nb1, 2), 1024, 0, stream>>>(
        cnt1, NP, incl1, bsum1, cnt2, NC, incl2, bsum2);
    k_scan2<<<dim3(1, 2), 1024, 0, stream>>>(bsum1, nb1, bsum2, nb2);
    k_scan3<<<dim3(ceil_div(maxN, 256), 2), 256, 0, stream>>>(
        cnt1, incl1, bsum1, NP, off1, cnt1, bcur1,
        cnt2, incl2, bsum2, NC, off2, cnt2, bcur2);
    k_partA<<<dim3(ceil_div(maxEp, PART_CHUNK), 2), 256, 0, stream>>>(
        NP, src_pp, dst_pp, E1, src_pc, dst_pc, elab_in, EPC, bcur1, bcur2, stg1, stg2);
    k_partB<<<NB1 + NB2, 256, 0, stream>>>(
        NB1, NP, off1, cnt1, stg1, e1src, E1, NC, off2, cnt2, stg2, epay, EPC);

    // fused input transforms: hl1 = x_p@W1l (h), hr1 = x_p@W1r (f), hl2 = x_p@W2l (h), hr2 = x_c@W2r (f)
    int tp = ceil_div(NP, 64), tc = ceil_div(NC, 64);
    GemmJobs J;
    J.x[0] = x_p; J.WT[0] = wt + 0 * 4096; J.b[0] = b1l; J.o[0] = hl1; J.n[0] = NP; J.half_out[0] = 1;
    J.x[1] = x_p; J.WT[1] = wt + 1 * 4096; J.b[1] = b1r; J.o[1] = hr1; J.n[1] = NP; J.half_out[1] = 0;
    J.x[2] = x_p; J.WT[2] = wt + 2 * 4096; J.b[2] = b2l; J.o[2] = hl2; J.n[2] = NP; J.half_out[2] = 1;
    J.x[3] = x_c; J.WT[3] = wt + 3 * 4096; J.b[3] = b2r; J.o[3] = hr2; J.n[3] = NC; J.half_out[3] = 0;
    J.tend[0] = tp; J.tend[1] = 2 * tp; J.tend[2] = 3 * tp; J.tend[3] = 3 * tp + tc;
    k_gemm_all<<<ceil_div(J.tend[3] * 64, 256), 256, 0, stream>>>(J);

    // conv1 -> (relu -> @W3l + b3l) -> hl3 (fp16)
    k_gat1<<<ceil_div(NP * 64, 256), 256, 0, stream>>>(
        hl1, hr1, off1, e1src, att1, bias1, W3l, b3l, hl3, NP);

    // conv2+conv3 fused -> d_out
    k_gat23<<<ceil_div(NC * 64, 256), 256, 0, stream>>>(
        hl2, hr2, hl3, off2, epay, We2, att2, bias2, W3r, b3r,
        We3, att3, bias3, Wlin, blin, out, NC);
}

// Round 11
// 589.360 us; speedup vs baseline: 3.5097x; 1.0019x over previous
//
#include <hip/hip_runtime.h>
#include <hip/hip_fp16.h>

static inline int ceil_div(int a, int b) { return (a + b - 1) / b; }

typedef _Float16 f16x2 __attribute__((ext_vector_type(2)));

#define PART_CHUNK 8192

// ================= CSR build =================

__global__ void k_count_all(int NP, const int* __restrict__ dst_pp, int EPP,
                            const int* __restrict__ dst_pc, int EPC,
                            int* __restrict__ cnt1, int* __restrict__ cnt2) {
    int e = blockIdx.x * blockDim.x + threadIdx.x;
    if (e < NP) atomicAdd(&cnt1[e], 1);  // self loop
    if (e < EPP) atomicAdd(&cnt1[dst_pp[e]], 1);
    if (e < EPC) atomicAdd(&cnt2[dst_pc[e]], 1);
}

__global__ void k_scan1(const int* c1, int n1, int* i1, int* bs1,
                        const int* c2, int n2, int* i2, int* bs2) {
    const int* cnt = blockIdx.y ? c2 : c1;
    int n = blockIdx.y ? n2 : n1;
    int* incl = blockIdx.y ? i2 : i1;
    int* bsum = blockIdx.y ? bs2 : bs1;
    if ((int)blockIdx.x * 1024 >= n) return;
    __shared__ int sm[1024];
    int tid = threadIdx.x;
    int i = blockIdx.x * 1024 + tid;
    sm[tid] = (i < n) ? cnt[i] : 0;
    __syncthreads();
    for (int off = 1; off < 1024; off <<= 1) {
        int t = (tid >= off) ? sm[tid - off] : 0;
        __syncthreads();
        sm[tid] += t;
        __syncthreads();
    }
    if (i < n) incl[i] = sm[tid];
    if (tid == 1023) bsum[blockIdx.x] = sm[1023];
}

__global__ void k_scan2(int* bs1, int nb1, int* bs2, int nb2) {
    int* bsum = blockIdx.y ? bs2 : bs1;
    int nb = blockIdx.y ? nb2 : nb1;
    __shared__ int sm[1024];
    int tid = threadIdx.x;
    sm[tid] = (tid < nb) ? bsum[tid] : 0;
    __syncthreads();
    for (int off = 1; off < 1024; off <<= 1) {
        int t = (tid >= off) ? sm[tid - off] : 0;
        __syncthreads();
        sm[tid] += t;
        __syncthreads();
    }
    if (tid < nb) bsum[tid] = sm[tid];
}

// also initializes per-bucket staging cursors bcur[b] = offs[b*512]
__global__ void k_scan3(const int* c1, const int* i1, const int* bs1, int n1, int* o1, int* u1, int* bc1,
                        const int* c2, const int* i2, const int* bs2, int n2, int* o2, int* u2, int* bc2) {
    const int* cnt = blockIdx.y ? c2 : c1;
    const int* incl = blockIdx.y ? i2 : i1;
    const int* bsum = blockIdx.y ? bs2 : bs1;
    int n = blockIdx.y ? n2 : n1;
    int* offs = blockIdx.y ? o2 : o1;
    int* cur = blockIdx.y ? u2 : u1;
    int* bcur = blockIdx.y ? bc2 : bc1;
    int i = blockIdx.x * blockDim.x + threadIdx.x;
    if (i >= n) return;
    int b = i >> 10;
    int inc = incl[i] + (b ? bsum[b - 1] : 0);
    int off = inc - cnt[i];
    offs[i] = off;
    cur[i] = off;
    if ((i & 511) == 0) bcur[i >> 9] = off;
    if (i == n - 1) offs[n] = inc;
}

// Phase A: radix-partition edges into 512-node dst-buckets. Per-workgroup LDS
// histogram + ONE global atomicAdd per (wg,bucket) reservation, then
// LDS-ranked scatter -> staging writes are ~300B contiguous runs.
__global__ __launch_bounds__(256) void k_partA(
    int NP, const int* __restrict__ src_pp, const int* __restrict__ dst_pp, int E1,
    const int* __restrict__ src_pc, const int* __restrict__ dst_pc,
    const float* __restrict__ lab, int EPC,
    int* __restrict__ bcur1, int* __restrict__ bcur2,
    uint2* __restrict__ stg1, uint2* __restrict__ stg2) {
    __shared__ int hist[256];
    __shared__ int base[256];
    int g = blockIdx.y;   // 0 = product graph (self+pp), 1 = customer graph (pc)
    int E = g ? EPC : E1;
    int e0 = blockIdx.x * PART_CHUNK;
    if (e0 >= E) return;
    int e1 = e0 + PART_CHUNK < E ? e0 + PART_CHUNK : E;
    int tid = threadIdx.x;
    hist[tid] = 0;
    __syncthreads();
    for (int i = e0 + tid; i < e1; i += 256) {
        int d = g ? dst_pc[i] : (i < NP ? i : dst_pp[i - NP]);
        atomicAdd(&hist[d >> 9], 1);
    }
    __syncthreads();
    int h = hist[tid];
    base[tid] = h ? atomicAdd((g ? bcur2 : bcur1) + tid, h) : 0;
    hist[tid] = 0;
    __syncthreads();
    uint2* stg = g ? stg2 : stg1;
    for (int i = e0 + tid; i < e1; i += 256) {
        int d; unsigned pay;
        if (g) {
            d = dst_pc[i];
            unsigned hh = (unsigned)__half_as_ushort(__float2half_rn(lab[i]));
            pay = (unsigned)src_pc[i] | (hh << 16);
        } else {
            int s;
            if (i < NP) { d = i; s = i; } else { d = dst_pp[i - NP]; s = src_pp[i - NP]; }
            pay = (unsigned)s << 7;
        }
        int b = d >> 9;
        int r = atomicAdd(&hist[b], 1);
        stg[base[b] + r] = make_uint2(pay, (unsigned)d);
    }
}

// Phase B: one workgroup per bucket; re-scatter into final CSR slots. Random
// writes confined to the bucket's CSR window (L2-resident). Also zero-pads
// 32 entries past each array end (clamp-free deep prefetch in gat).
__global__ __launch_bounds__(256) void k_partB(
    int NB1, int NP, const int* __restrict__ off1, int* __restrict__ cur1,
    const uint2* __restrict__ stg1, unsigned* __restrict__ e1src, int E1,
    int NC, const int* __restrict__ off2, int* __restrict__ cur2,
    const uint2* __restrict__ stg2, unsigned* __restrict__ epay, int EPC) {
    int b = blockIdx.x;
    if (b == 0 && threadIdx.x < 32) {
        e1src[E1 + threadIdx.x] = 0u;
        epay[EPC + threadIdx.x] = 0u;
    }
    if (b < NB1) {
        int n0 = b << 9;
        int n1 = (n0 + 512) < NP ? (n0 + 512) : NP;
        int lo = off1[n0], hi = off1[n1];
        for (int i = lo + threadIdx.x; i < hi; i += 256) {
            uint2 r = stg1[i];
            int pos = atomicAdd(&cur1[r.y], 1);
            e1src[pos] = r.x;
        }
    } else {
        int bb = b - NB1;
        int n0 = bb << 9;
        int n1 = (n0 + 512) < NC ? (n0 + 512) : NC;
        int lo = off2[n0], hi = off2[n1];
        for (int i = lo + threadIdx.x; i < hi; i += 256) {
            uint2 r = stg2[i];
            int pos = atomicAdd(&cur2[r.y], 1);
            epay[pos] = r.x;
        }
    }
}

// ================= weight transpose =================

__global__ void k_transpose_all(const float* s0, const float* s1, const float* s2,
                                const float* s3, float* __restrict__ wt) {
    const float* S[4] = {s0, s1, s2, s3};
    const float* W = S[blockIdx.y];
    int j = threadIdx.x, k = blockIdx.x;
    wt[blockIdx.y * 4096 + k * 64 + j] = W[j * 64 + k];
}

// ================= helpers =================

__device__ __forceinline__ unsigned pkh_(float a, float b) {
    __half2 h = __floats2half2_rn(a, b);
    return *(unsigned*)&h;
}

__device__ __forceinline__ f16x2 pkc_(float a, float b) {
    f16x2 r;
    r.x = (_Float16)a;
    r.y = (_Float16)b;
    return r;
}

__device__ __forceinline__ uint2 ld8_(const void* p, unsigned boff) {
    return *(const uint2*)((const char*)p + boff);
}

__device__ __forceinline__ float4 unpk_(uint2 u) {
    f16x2 h01 = *(f16x2*)&u.x, h23 = *(f16x2*)&u.y;
    return make_float4((float)h01.x, (float)h01.y, (float)h23.x, (float)h23.y);
}

__device__ __forceinline__ float fdot2_(f16x2 a, f16x2 b, float c) {
#if __has_builtin(__builtin_amdgcn_fdot2)
    return __builtin_amdgcn_fdot2(a, b, c, false);
#else
    return fmaf((float)a.x, (float)b.x, fmaf((float)a.y, (float)b.y, c));
#endif
}

// ================= fused input-transform GEMMs =================

__device__ __forceinline__ void gemm_one(const float xr[64], int row, bool valid,
                                         const float* __restrict__ WT,
                                         const float* __restrict__ b,
                                         void* __restrict__ o, int half_out) {
    for (int k4 = 0; k4 < 64; k4 += 4) {
        float a0 = b[k4 + 0], a1 = b[k4 + 1], a2 = b[k4 + 2], a3 = b[k4 + 3];
#pragma unroll
        for (int j = 0; j < 64; ++j) {
            float xv = xr[j];
            a0 = fmaf(xv, WT[(k4 + 0) * 64 + j], a0);
            a1 = fmaf(xv, WT[(k4 + 1) * 64 + j], a1);
            a2 = fmaf(xv, WT[(k4 + 2) * 64 + j], a2);
            a3 = fmaf(xv, WT[(k4 + 3) * 64 + j], a3);
        }
        if (valid) {
            if (half_out) {
                *(uint2*)((char*)o + (size_t)row * 128 + k4 * 2) =
                    make_uint2(pkh_(a0, a1), pkh_(a2, a3));
            } else {
                *(float4*)((float*)o + (size_t)row * 64 + k4) = make_float4(a0, a1, a2, a3);
            }
        }
    }
}

struct GemmJobs {
    const float* x[4]; const float* WT[4]; const float* b[4]; void* o[4];
    int n[4]; int tend[4]; int half_out[4];
};

__global__ __launch_bounds__(256) void k_gemm_all(GemmJobs J) {
    int lane = threadIdx.x & 63;
    int gtile = (blockIdx.x * blockDim.x + threadIdx.x) >> 6;
    if (gtile >= J.tend[3]) return;
    const float* x; const float* WT; const float* b; void* o; int n; int base; int ho;
    if (gtile < J.tend[0]) { x = J.x[0]; WT = J.WT[0]; b = J.b[0]; o = J.o[0]; n = J.n[0]; base = 0; ho = J.half_out[0]; }
    else if (gtile < J.tend[1]) { x = J.x[1]; WT = J.WT[1]; b = J.b[1]; o = J.o[1]; n = J.n[1]; base = J.tend[0]; ho = J.half_out[1]; }
    else if (gtile < J.tend[2]) { x = J.x[2]; WT = J.WT[2]; b = J.b[2]; o = J.o[2]; n = J.n[2]; base = J.tend[1]; ho = J.half_out[2]; }
    else { x = J.x[3]; WT = J.WT[3]; b = J.b[3]; o = J.o[3]; n = J.n[3]; base = J.tend[2]; ho = J.half_out[3]; }
    int row = (gtile - base) * 64 + lane;
    bool valid = row < n;
    int rr = valid ? row : 0;
    float xr[64];
    const float4* xp = (const float4*)(x + (size_t)rr * 64);
#pragma unroll
    for (int i = 0; i < 16; ++i) {
        float4 v = xp[i];
        xr[4 * i + 0] = v.x; xr[4 * i + 1] = v.y; xr[4 * i + 2] = v.z; xr[4 * i + 3] = v.w;
    }
    gemm_one(xr, row, valid, WT, b, o, ho);
}

// ================= GATv2 building blocks =================

template <int CTRL>
__device__ __forceinline__ float dppadd_(float x) {
    int y = __builtin_amdgcn_update_dpp(0, __float_as_int(x), CTRL, 0xF, 0xF, true);
    return x + __int_as_float(y);
}

// sum across each aligned 16-lane group (all lanes get the total); VALU-only
__device__ __forceinline__ float red16_(float c) {
    c = dppadd_<0xB1>(c);   // quad_perm xor1
    c = dppadd_<0x4E>(c);   // quad_perm xor2
    c = dppadd_<0x124>(c);  // row_ror:4
    c = dppadd_<0x128>(c);  // row_ror:8
    return c;
}

template <int HAS_EF>
__device__ __forceinline__ unsigned boff_(unsigned pr) {
    return HAS_EF ? ((pr & 0xFFFFu) << 7) : pr;  // pp payloads pre-shifted
}

// Edge loop over fp16 rows; message/dot math in packed half2 (v_pk_* + v_dot2).
// No max-subtraction (scores O(+-5): fp32 exp safe). att pre-scaled by log2(e)
// and pre-converted to f16x2. slot = lane>>4 (4 edges in flight per iter),
// g = lane&15. DEPTH-4 gather pipeline (4 feature loads + 5 payloads in
// flight, register rotation with static indices). Payload arrays are
// zero-padded 32 entries -> no clamping anywhere.
template <int HAS_EF>
__device__ __forceinline__ void gat_pass(
    const void* __restrict__ hl, const unsigned* __restrict__ pay,
    int beg, int end, int slot, int g,
    f16x2 hr01, f16x2 hr23, f16x2 att01, f16x2 att23,
    f16x2 we01, f16x2 we23,
    float& s_run, float4& acc) {
    s_run = 0.f;
    acc = make_float4(0.f, 0.f, 0.f, 0.f);
    if (beg >= end) return;
    unsigned goff = (unsigned)g * 8u;
    int p = beg + slot;
    unsigned pr0 = pay[p], pr1 = pay[p + 4], pr2 = pay[p + 8],
             pr3 = pay[p + 12], pr4 = pay[p + 16];
    uint2 u0 = ld8_(hl, boff_<HAS_EF>(pr0) + goff);
    uint2 u1 = ld8_(hl, boff_<HAS_EF>(pr1) + goff);
    uint2 u2 = ld8_(hl, boff_<HAS_EF>(pr2) + goff);
    uint2 u3 = ld8_(hl, boff_<HAS_EF>(pr3) + goff);
    int pend = end + slot;
    for (; p < pend; p += 4) {
        unsigned prn = pay[p + 20];
        uint2 un = ld8_(hl, boff_<HAS_EF>(pr4) + goff);
        f16x2 m01 = *(f16x2*)&u0.x + hr01;
        f16x2 m23 = *(f16x2*)&u0.y + hr23;
        if (HAS_EF) {
            unsigned uh = pr0 & 0xFFFF0000u;
            unsigned lbu = uh | (uh >> 16);
            f16x2 lb2 = *(f16x2*)&lbu;
            m01 = lb2 * we01 + m01;   // v_pk_fma_f16
            m23 = lb2 * we23 + m23;
        }
        m01 = __builtin_elementwise_max(m01, m01 * (_Float16)0.2f);  // leaky(0.2)
        m23 = __builtin_elementwise_max(m23, m23 * (_Float16)0.2f);
        float c = fdot2_(m01, att01, 0.f);
        c = fdot2_(m23, att23, c);
        c = red16_(c);
        float w = (p < end) ? exp2f(c) : 0.f;
        s_run += w;
        float4 h = unpk_(u0);
        acc.x = fmaf(w, h.x, acc.x);
        acc.y = fmaf(w, h.y, acc.y);
        acc.z = fmaf(w, h.z, acc.z);
        acc.w = fmaf(w, h.w, acc.w);
        pr0 = pr1; pr1 = pr2; pr2 = pr3; pr3 = pr4; pr4 = prn;
        u0 = u1; u1 = u2; u2 = u3; u3 = un;
    }
}

// cross-slot totals: pure butterfly adds
__device__ __forceinline__ void slot_merge(float& s, float4& a) {
#pragma unroll
    for (int mask = 16; mask <= 32; mask <<= 1) {
        s += __shfl_xor(s, mask, 64);
        a.x += __shfl_xor(a.x, mask, 64);
        a.y += __shfl_xor(a.y, mask, 64);
        a.z += __shfl_xor(a.z, mask, 64);
        a.w += __shfl_xor(a.w, mask, 64);
    }
}

__device__ __forceinline__ void finish_row(float s_run, float4 a,
                                           const float* __restrict__ bias, int g,
                                           float o4[4]) {
    float inv = 1.f / (s_run + 1e-16f);
    float4 b4 = *(const float4*)(bias + g * 4);
    o4[0] = fmaxf(fmaf(a.x, inv, b4.x), 0.f);
    o4[1] = fmaxf(fmaf(a.y, inv, b4.y), 0.f);
    o4[2] = fmaxf(fmaf(a.z, inv, b4.z), 0.f);
    o4[3] = fmaxf(fmaf(a.w, inv, b4.w), 0.f);
}

// In-wave GEMV row@W via LDS row broadcast: slot0 writes the 64-float row,
// each lane reads its slot's 16 j values (4x ds_read_b128), 64 fma, cross-slot
// butterfly. Same-wave LDS RAW: DS ops are in-order per wave; fences stop
// compiler reordering.
__device__ __forceinline__ float4 gemv64(const float o4[4], float* __restrict__ lds_row,
                                         int slot, int g, const float* __restrict__ W) {
    if (slot == 0) *(float4*)(lds_row + 4 * g) = make_float4(o4[0], o4[1], o4[2], o4[3]);
    __asm__ volatile("" ::: "memory");
    __builtin_amdgcn_wave_barrier();
    float4 r0 = *(const float4*)(lds_row + slot * 16 + 0);
    float4 r1 = *(const float4*)(lds_row + slot * 16 + 4);
    float4 r2 = *(const float4*)(lds_row + slot * 16 + 8);
    float4 r3 = *(const float4*)(lds_row + slot * 16 + 12);
    __asm__ volatile("" ::: "memory");
    __builtin_amdgcn_wave_barrier();
    float rv[16] = {r0.x, r0.y, r0.z, r0.w, r1.x, r1.y, r1.z, r1.w,
                    r2.x, r2.y, r2.z, r2.w, r3.x, r3.y, r3.z, r3.w};
    const float* Wp = W + slot * 16 * 64 + g * 4;
    float a0 = 0.f, a1 = 0.f, a2 = 0.f, a3 = 0.f;
#pragma unroll
    for (int t = 0; t < 16; ++t) {
        float4 w4 = *(const float4*)(Wp + t * 64);
        a0 = fmaf(rv[t], w4.x, a0); a1 = fmaf(rv[t], w4.y, a1);
        a2 = fmaf(rv[t], w4.z, a2); a3 = fmaf(rv[t], w4.w, a3);
    }
    a0 += __shfl_xor(a0, 16, 64); a0 += __shfl_xor(a0, 32, 64);
    a1 += __shfl_xor(a1, 16, 64); a1 += __shfl_xor(a1, 32, 64);
    a2 += __shfl_xor(a2, 16, 64); a2 += __shfl_xor(a2, 32, 64);
    a3 += __shfl_xor(a3, 16, 64); a3 += __shfl_xor(a3, 32, 64);
    return make_float4(a0, a1, a2, a3);
}

// conv1 (products): GAT + relu + @W3l + b3l -> hl3 (fp16)
__global__ __launch_bounds__(256) void k_gat1(
    const void* __restrict__ hl, const float* __restrict__ hr,
    const int* __restrict__ offs, const unsigned* __restrict__ esrc,
    const float* __restrict__ att, const float* __restrict__ bias,
    const float* __restrict__ W2, const float* __restrict__ b2,
    void* __restrict__ out2, int ndst) {
    __shared__ float rowbuf[4][64];
    int wid = (blockIdx.x * blockDim.x + threadIdx.x) >> 6;
    if (wid >= ndst) return;
    int lane = threadIdx.x & 63, slot = lane >> 4, g = lane & 15;
    float* lrow = rowbuf[threadIdx.x >> 6];
    float4 hrf = *(const float4*)(hr + (size_t)wid * 64 + g * 4);
    f16x2 hr01 = pkc_(hrf.x, hrf.y), hr23 = pkc_(hrf.z, hrf.w);
    float4 at = *(const float4*)(att + g * 4);
    const float L2E = 1.44269504f;
    f16x2 att01 = pkc_(at.x * L2E, at.y * L2E), att23 = pkc_(at.z * L2E, at.w * L2E);
    int beg = offs[wid], end = offs[wid + 1];
    float s; float4 a;
    gat_pass<0>(hl, esrc, beg, end, slot, g, hr01, hr23, att01, att23, att01, att23, s, a);
    slot_merge(s, a);
    float o4[4];
    finish_row(s, a, bias, g, o4);
    float4 o = gemv64(o4, lrow, slot, g, W2);
    float4 bb = *(const float4*)(b2 + g * 4);
    o.x += bb.x; o.y += bb.y; o.z += bb.z; o.w += bb.w;
    if (slot == 0)
        *(uint2*)((char*)out2 + (size_t)wid * 128 + g * 8) =
            make_uint2(pkh_(o.x, o.y), pkh_(o.z, o.w));
}

// conv2 + conv3 fused per customer node
__global__ __launch_bounds__(256) void k_gat23(
    const void* __restrict__ hl2, const float* __restrict__ hr2,
    const void* __restrict__ hl3,
    const int* __restrict__ offs, const unsigned* __restrict__ epay,
    const float* __restrict__ We2, const float* __restrict__ att2, const float* __restrict__ bias2,
    const float* __restrict__ W3r, const float* __restrict__ b3r,
    const float* __restrict__ We3, const float* __restrict__ att3, const float* __restrict__ bias3,
    const float* __restrict__ Wlin, const float* __restrict__ blin,
    float* __restrict__ outp, int ndst) {
    __shared__ float rowbuf[4][64];
    int wid = (blockIdx.x * blockDim.x + threadIdx.x) >> 6;
    if (wid >= ndst) return;
    int lane = threadIdx.x & 63, slot = lane >> 4, g = lane & 15;
    float* lrow = rowbuf[threadIdx.x >> 6];
    int beg = offs[wid], end = offs[wid + 1];
    const float L2E = 1.44269504f;
    // ---- conv2 ----
    float4 hrf = *(const float4*)(hr2 + (size_t)wid * 64 + g * 4);
    f16x2 hr01 = pkc_(hrf.x, hrf.y), hr23 = pkc_(hrf.z, hrf.w);
    float4 at = *(const float4*)(att2 + g * 4);
    f16x2 att01 = pkc_(at.x * L2E, at.y * L2E), att23 = pkc_(at.z * L2E, at.w * L2E);
    float4 wef = *(const float4*)(We2 + g * 4);
    f16x2 we01 = pkc_(wef.x, wef.y), we23 = pkc_(wef.z, wef.w);
    float s; float4 a;
    gat_pass<1>(hl2, epay, beg, end, slot, g, hr01, hr23, att01, att23, we01, we23, s, a);
    slot_merge(s, a);
    float o4[4];
    finish_row(s, a, bias2, g, o4);
    float4 h3 = gemv64(o4, lrow, slot, g, W3r);
    float4 bb = *(const float4*)(b3r + g * 4);
    h3.x += bb.x; h3.y += bb.y; h3.z += bb.z; h3.w += bb.w;
    // ---- conv3 ----
    hr01 = pkc_(h3.x, h3.y); hr23 = pkc_(h3.z, h3.w);
    at = *(const float4*)(att3 + g * 4);
    att01 = pkc_(at.x * L2E, at.y * L2E); att23 = pkc_(at.z * L2E, at.w * L2E);
    wef = *(const float4*)(We3 + g * 4);
    we01 = pkc_(wef.x, wef.y); we23 = pkc_(wef.z, wef.w);
    gat_pass<1>(hl3, epay, beg, end, slot, g, hr01, hr23, att01, att23, we01, we23, s, a);
    slot_merge(s, a);
    finish_row(s, a, bias3, g, o4);
    float4 o = gemv64(o4, lrow, slot, g, Wlin);
    float4 bl = *(const float4*)(blin + g * 4);
    o.x += bl.x; o.y += bl.y; o.z += bl.z; o.w += bl.w;
    if (slot == 0) *(float4*)(outp + (size_t)wid * 64 + g * 4) = o;
}

// ================= launch =================

extern "C" void kernel_launch(void* const* d_in, const int* in_sizes, int n_in,
                              void* d_out, int out_size, void* d_ws, size_t ws_size,
                              hipStream_t stream) {
    const float* x_p = (const float*)d_in[0];
    const float* x_c = (const float*)d_in[1];
    const float* elab_in = (const float*)d_in[2];
    const int* src_pp = (const int*)d_in[3];
    const int* dst_pp = (const int*)d_in[4];
    const int* src_pc = (const int*)d_in[5];
    const int* dst_pc = (const int*)d_in[6];
    const float* W1l = (const float*)d_in[7];
    const float* b1l = (const float*)d_in[8];
    const float* W1r = (const float*)d_in[9];
    const float* b1r = (const float*)d_in[10];
    const float* att1 = (const float*)d_in[11];
    const float* bias1 = (const float*)d_in[12];
    const float* W2l = (const float*)d_in[13];
    const float* b2l = (const float*)d_in[14];
    const float* W2r = (const float*)d_in[15];
    const float* b2r = (const float*)d_in[16];
    const float* We2 = (const float*)d_in[17];
    const float* att2 = (const float*)d_in[18];
    const float* bias2 = (const float*)d_in[19];
    const float* W3l = (const float*)d_in[20];
    const float* b3l = (const float*)d_in[21];
    const float* W3r = (const float*)d_in[22];
    const float* b3r = (const float*)d_in[23];
    const float* We3 = (const float*)d_in[24];
    const float* att3 = (const float*)d_in[25];
    const float* bias3 = (const float*)d_in[26];
    const float* Wlin = (const float*)d_in[27];
    const float* blin = (const float*)d_in[28];
    float* out = (float*)d_out;

    const int NP = in_sizes[0] / 64;
    const int NC = in_sizes[1] / 64;
    const int EPP = in_sizes[3];
    const int EPC = in_sizes[5];
    const int E1 = EPP + NP;
    const int NB1 = ceil_div(NP, 512), NB2 = ceil_div(NC, 512);

    // workspace layout (256B-aligned chunks)
    char* w = (char*)d_ws;
    auto alloc = [&](size_t bytes) { char* r = w; w += (bytes + 255) & ~(size_t)255; return r; };
    void* hl1 = alloc((size_t)NP * 128);       // fp16
    void* hl2 = alloc((size_t)NP * 128);       // fp16
    void* hl3 = alloc((size_t)NP * 128);       // fp16 (conv1-fused output)
    float* hr1 = (float*)alloc((size_t)NP * 256);
    float* hr2 = (float*)alloc((size_t)NC * 256);
    float* wt = (float*)alloc(4 * 4096 * 4);
    unsigned* epay = (unsigned*)alloc((size_t)(EPC + 32) * 4);
    unsigned* e1src = (unsigned*)alloc((size_t)(E1 + 32) * 4);
    uint2* stg1 = (uint2*)alloc((size_t)E1 * 8);
    uint2* stg2 = (uint2*)alloc((size_t)EPC * 8);
    int* off1 = (int*)alloc((size_t)(NP + 1) * 4);
    int* cnt1 = (int*)alloc((size_t)NP * 4);
    int* off2 = (int*)alloc((size_t)(NC + 1) * 4);
    int* cnt2 = (int*)alloc((size_t)NC * 4);
    int* incl1 = (int*)alloc((size_t)NP * 4);
    int* incl2 = (int*)alloc((size_t)NC * 4);
    int* bsum1 = (int*)alloc(1024 * 4);
    int* bsum2 = (int*)alloc(1024 * 4);
    int* bcur1 = (int*)alloc(256 * 4);
    int* bcur2 = (int*)alloc(256 * 4);

    int nb1 = ceil_div(NP, 1024), nb2 = ceil_div(NC, 1024);
    int maxE = EPC > EPP ? EPC : EPP; if (NP > maxE) maxE = NP;
    int maxN = NC > NP ? NC : NP;
    int maxEp = EPC > E1 ? EPC : E1;

    (void)hipMemsetAsync(cnt1, 0, (size_t)NP * 4, stream);
    (void)hipMemsetAsync(cnt2, 0, (size_t)NC * 4, stream);

    k_transpose_all<<<dim3(64, 4), 64, 0, stream>>>(W1l, W1r, W2l, W2r, wt);

    k_count_all<<<ceil_div(maxE, 256), 256, 0, stream>>>(NP, dst_pp, EPP, dst_pc, EPC, cnt1, cnt2);
    k_scan1<<<dim3(nb2 > nb1 ? nb2 : nb1, 2), 1024, 0, stream>>>(
        cnt1, NP, incl1, bsum1, cnt2, NC, incl2, bsum2);
    k_scan2<<<dim3(1, 2), 1024, 0, stream>>>(bsum1, nb1, bsum2, nb2);
    k_scan3<<<dim3(ceil_div(maxN, 256), 2), 256, 0, stream>>>(
        cnt1, incl1, bsum1, NP, off1, cnt1, bcur1,
        cnt2, incl2, bsum2, NC, off2, cnt2, bcur2);
    k_partA<<<dim3(ceil_div(maxEp, PART_CHUNK), 2), 256, 0, stream>>>(
        NP, src_pp, dst_pp, E1, src_pc, dst_pc, elab_in, EPC, bcur1, bcur2, stg1, stg2);
    k_partB<<<NB1 + NB2, 256, 0, stream>>>(
        NB1, NP, off1, cnt1, stg1, e1src, E1, NC, off2, cnt2, stg2, epay, EPC);

    // fused input transforms: hl1 = x_p@W1l (h), hr1 = x_p@W1r (f), hl2 = x_p@W2l (h), hr2 = x_c@W2r (f)
    int tp = ceil_div(NP, 64), tc = ceil_div(NC, 64);
    GemmJobs J;
    J.x[0] = x_p; J.WT[0] = wt + 0 * 4096; J.b[0] = b1l; J.o[0] = hl1; J.n[0] = NP; J.half_out[0] = 1;
    J.x[1] = x_p; J.WT[1] = wt + 1 * 4096; J.b[1] = b1r; J.o[1] = hr1; J.n[1] = NP; J.half_out[1] = 0;
    J.x[2] = x_p; J.WT[2] = wt + 2 * 4096; J.b[2] = b2l; J.o[2] = hl2; J.n[2] = NP; J.half_out[2] = 1;
    J.x[3] = x_c; J.WT[3] = wt + 3 * 4096; J.b[3] = b2r; J.o[3] = hr2; J.n[3] = NC; J.half_out[3] = 0;
    J.tend[0] = tp; J.tend[1] = 2 * tp; J.tend[2] = 3 * tp; J.tend[3] = 3 * tp + tc;
    k_gemm_all<<<ceil_div(J.tend[3] * 64, 256), 256, 0, stream>>>(J);

    // conv1 -> (relu -> @W3l + b3l) -> hl3 (fp16)
    k_gat1<<<ceil_div(NP * 64, 256), 256, 0, stream>>>(
        hl1, hr1, off1, e1src, att1, bias1, W3l, b3l, hl3, NP);

    // conv2+conv3 fused -> d_out
    k_gat23<<<ceil_div(NC * 64, 256), 256, 0, stream>>>(
        hl2, hr2, hl3, off2, epay, We2, att2, bias2, W3r, b3r,
        We3, att3, bias3, Wlin, blin, out, NC);
}

// Round 12
// 463.929 us; speedup vs baseline: 4.4586x; 1.2704x over previous
//
#include <hip/hip_runtime.h>
#include <hip/hip_fp16.h>

static inline int ceil_div(int a, int b) { return (a + b - 1) / b; }

typedef _Float16 f16x2 __attribute__((ext_vector_type(2)));

#define PART_CHUNK 8192

// ================= CSR build (bucketed, no per-node global atomics) =================

// per-bucket histogram of dst (512 nodes/bucket): LDS hist + one global add per (wg,bucket)
__global__ __launch_bounds__(256) void k_bhist(
    const int* __restrict__ dst_pp, int EPP,
    const int* __restrict__ dst_pc, int EPC,
    int* __restrict__ btot1, int* __restrict__ btot2) {
    __shared__ int hist[256];
    int g = blockIdx.y;
    const int* dst = g ? dst_pc : dst_pp;
    int E = g ? EPC : EPP;
    int e0 = blockIdx.x * PART_CHUNK;
    if (e0 >= E) return;
    int e1 = e0 + PART_CHUNK < E ? e0 + PART_CHUNK : E;
    hist[threadIdx.x] = 0;
    __syncthreads();
    for (int i = e0 + threadIdx.x; i < e1; i += 256)
        atomicAdd(&hist[dst[i] >> 9], 1);
    __syncthreads();
    int h = hist[threadIdx.x];
    if (h) atomicAdd((g ? btot2 : btot1) + threadIdx.x, h);
}

// scan bucket totals -> bucket bases + staging cursors. Graph0 adds self loops
// analytically (+nodes-in-bucket). One 256-thread block per graph.
__global__ void k_bscan(int NP, int NB1, const int* __restrict__ btot1,
                        int* __restrict__ bbase1, int* __restrict__ bcur1,
                        int NC, int NB2, const int* __restrict__ btot2,
                        int* __restrict__ bbase2, int* __restrict__ bcur2) {
    __shared__ int sm[256];
    int g = blockIdx.y;
    int NB = g ? NB2 : NB1;
    const int* btot = g ? btot2 : btot1;
    int* bbase = g ? bbase2 : bbase1;
    int* bcur = g ? bcur2 : bcur1;
    int tid = threadIdx.x;
    int v = 0;
    if (tid < NB) {
        v = btot[tid];
        if (!g) {
            int self = NP - (tid << 9);
            if (self > 512) self = 512;
            if (self < 0) self = 0;
            v += self;
        }
    }
    sm[tid] = v;
    __syncthreads();
    for (int off = 1; off < 256; off <<= 1) {
        int t = (tid >= off) ? sm[tid - off] : 0;
        __syncthreads();
        sm[tid] += t;
        __syncthreads();
    }
    if (tid < NB) {
        int base = tid ? sm[tid - 1] : 0;
        bbase[tid] = base;
        bcur[tid] = base;
    }
    if (tid == NB) bbase[tid] = sm[NB - 1];
}

// Phase A: radix-partition edges into 512-node dst-buckets. Per-workgroup LDS
// histogram + ONE global atomicAdd per (wg,bucket) reservation, then
// LDS-ranked scatter -> staging writes are ~300B contiguous runs.
__global__ __launch_bounds__(256) void k_partA(
    int NP, const int* __restrict__ src_pp, const int* __restrict__ dst_pp, int E1,
    const int* __restrict__ src_pc, const int* __restrict__ dst_pc,
    const float* __restrict__ lab, int EPC,
    int* __restrict__ bcur1, int* __restrict__ bcur2,
    uint2* __restrict__ stg1, uint2* __restrict__ stg2) {
    __shared__ int hist[256];
    __shared__ int base[256];
    int g = blockIdx.y;   // 0 = product graph (self+pp), 1 = customer graph (pc)
    int E = g ? EPC : E1;
    int e0 = blockIdx.x * PART_CHUNK;
    if (e0 >= E) return;
    int e1 = e0 + PART_CHUNK < E ? e0 + PART_CHUNK : E;
    int tid = threadIdx.x;
    hist[tid] = 0;
    __syncthreads();
    for (int i = e0 + tid; i < e1; i += 256) {
        int d = g ? dst_pc[i] : (i < NP ? i : dst_pp[i - NP]);
        atomicAdd(&hist[d >> 9], 1);
    }
    __syncthreads();
    int h = hist[tid];
    base[tid] = h ? atomicAdd((g ? bcur2 : bcur1) + tid, h) : 0;
    hist[tid] = 0;
    __syncthreads();
    uint2* stg = g ? stg2 : stg1;
    for (int i = e0 + tid; i < e1; i += 256) {
        int d; unsigned pay;
        if (g) {
            d = dst_pc[i];
            unsigned hh = (unsigned)__half_as_ushort(__float2half_rn(lab[i]));
            pay = (unsigned)src_pc[i] | (hh << 16);
        } else {
            int s;
            if (i < NP) { d = i; s = i; } else { d = dst_pp[i - NP]; s = src_pp[i - NP]; }
            pay = (unsigned)s << 7;
        }
        int b = d >> 9;
        int r = atomicAdd(&hist[b], 1);
        stg[base[b] + r] = make_uint2(pay, (unsigned)d);
    }
}

// Phase B2: one workgroup per bucket. LDS per-node count -> LDS scan ->
// write off[] (sequential) -> scatter to final CSR slots via LDS cursors.
// No per-node global atomics anywhere. Also zero-pads 32 entries past each
// payload array end (clamp-free deep prefetch in gat).
__global__ __launch_bounds__(512) void k_partB2(
    int NB1, int NP, const int* __restrict__ bbase1, const uint2* __restrict__ stg1,
    unsigned* __restrict__ e1src, int* __restrict__ off1, int E1,
    int NC, const int* __restrict__ bbase2, const uint2* __restrict__ stg2,
    unsigned* __restrict__ epay, int* __restrict__ off2, int EPC) {
    __shared__ int cnt[512];
    __shared__ int cur[512];
    int b = blockIdx.x;
    int tid = threadIdx.x;
    if (b == 0 && tid < 32) {
        e1src[E1 + tid] = 0u;
        epay[EPC + tid] = 0u;
    }
    int n, n0, lo, hi;
    const uint2* stg; unsigned* dstp; int* off;
    if (b < NB1) {
        n = NP; n0 = b << 9; lo = bbase1[b]; hi = bbase1[b + 1];
        stg = stg1; dstp = e1src; off = off1;
    } else {
        int bb = b - NB1;
        n = NC; n0 = bb << 9; lo = bbase2[bb]; hi = bbase2[bb + 1];
        stg = stg2; dstp = epay; off = off2;
    }
    cnt[tid] = 0;
    __syncthreads();
    for (int i = lo + tid; i < hi; i += 512)
        atomicAdd(&cnt[stg[i].y & 511], 1);
    __syncthreads();
    int c0 = cnt[tid];
    for (int off_ = 1; off_ < 512; off_ <<= 1) {
        int t = (tid >= off_) ? cnt[tid - off_] : 0;
        __syncthreads();
        cnt[tid] += t;
        __syncthreads();
    }
    int pos0 = lo + cnt[tid] - c0;   // global CSR start for node n0+tid
    cur[tid] = pos0;
    int node = n0 + tid;
    if (node < n) off[node] = pos0;
    if (node == n - 1) off[n] = hi;
    __syncthreads();
    for (int i = lo + tid; i < hi; i += 512) {
        uint2 r = stg[i];
        int pos = atomicAdd(&cur[r.y & 511], 1);
        dstp[pos] = r.x;
    }
}

// ================= weight transpose =================

__global__ void k_transpose_all(const float* s0, const float* s1, const float* s2,
                                const float* s3, float* __restrict__ wt) {
    const float* S[4] = {s0, s1, s2, s3};
    const float* W = S[blockIdx.y];
    int j = threadIdx.x, k = blockIdx.x;
    wt[blockIdx.y * 4096 + k * 64 + j] = W[j * 64 + k];
}

// ================= helpers =================

__device__ __forceinline__ unsigned pkh_(float a, float b) {
    __half2 h = __floats2half2_rn(a, b);
    return *(unsigned*)&h;
}

__device__ __forceinline__ f16x2 pkc_(float a, float b) {
    f16x2 r;
    r.x = (_Float16)a;
    r.y = (_Float16)b;
    return r;
}

__device__ __forceinline__ uint2 ld8_(const void* p, unsigned boff) {
    return *(const uint2*)((const char*)p + boff);
}

__device__ __forceinline__ float4 unpk_(uint2 u) {
    f16x2 h01 = *(f16x2*)&u.x, h23 = *(f16x2*)&u.y;
    return make_float4((float)h01.x, (float)h01.y, (float)h23.x, (float)h23.y);
}

__device__ __forceinline__ float fdot2_(f16x2 a, f16x2 b, float c) {
#if __has_builtin(__builtin_amdgcn_fdot2)
    return __builtin_amdgcn_fdot2(a, b, c, false);
#else
    return fmaf((float)a.x, (float)b.x, fmaf((float)a.y, (float)b.y, c));
#endif
}

// ================= fused input-transform GEMMs =================

__device__ __forceinline__ void gemm_one(const float xr[64], int row, bool valid,
                                         const float* __restrict__ WT,
                                         const float* __restrict__ b,
                                         void* __restrict__ o, int half_out) {
    for (int k4 = 0; k4 < 64; k4 += 4) {
        float a0 = b[k4 + 0], a1 = b[k4 + 1], a2 = b[k4 + 2], a3 = b[k4 + 3];
#pragma unroll
        for (int j = 0; j < 64; ++j) {
            float xv = xr[j];
            a0 = fmaf(xv, WT[(k4 + 0) * 64 + j], a0);
            a1 = fmaf(xv, WT[(k4 + 1) * 64 + j], a1);
            a2 = fmaf(xv, WT[(k4 + 2) * 64 + j], a2);
            a3 = fmaf(xv, WT[(k4 + 3) * 64 + j], a3);
        }
        if (valid) {
            if (half_out) {
                *(uint2*)((char*)o + (size_t)row * 128 + k4 * 2) =
                    make_uint2(pkh_(a0, a1), pkh_(a2, a3));
            } else {
                *(float4*)((float*)o + (size_t)row * 64 + k4) = make_float4(a0, a1, a2, a3);
            }
        }
    }
}

struct GemmJobs {
    const float* x[4]; const float* WT[4]; const float* b[4]; void* o[4];
    int n[4]; int tend[4]; int half_out[4];
};

__global__ __launch_bounds__(256) void k_gemm_all(GemmJobs J) {
    int lane = threadIdx.x & 63;
    int gtile = (blockIdx.x * blockDim.x + threadIdx.x) >> 6;
    if (gtile >= J.tend[3]) return;
    const float* x; const float* WT; const float* b; void* o; int n; int base; int ho;
    if (gtile < J.tend[0]) { x = J.x[0]; WT = J.WT[0]; b = J.b[0]; o = J.o[0]; n = J.n[0]; base = 0; ho = J.half_out[0]; }
    else if (gtile < J.tend[1]) { x = J.x[1]; WT = J.WT[1]; b = J.b[1]; o = J.o[1]; n = J.n[1]; base = J.tend[0]; ho = J.half_out[1]; }
    else if (gtile < J.tend[2]) { x = J.x[2]; WT = J.WT[2]; b = J.b[2]; o = J.o[2]; n = J.n[2]; base = J.tend[1]; ho = J.half_out[2]; }
    else { x = J.x[3]; WT = J.WT[3]; b = J.b[3]; o = J.o[3]; n = J.n[3]; base = J.tend[2]; ho = J.half_out[3]; }
    int row = (gtile - base) * 64 + lane;
    bool valid = row < n;
    int rr = valid ? row : 0;
    float xr[64];
    const float4* xp = (const float4*)(x + (size_t)rr * 64);
#pragma unroll
    for (int i = 0; i < 16; ++i) {
        float4 v = xp[i];
        xr[4 * i + 0] = v.x; xr[4 * i + 1] = v.y; xr[4 * i + 2] = v.z; xr[4 * i + 3] = v.w;
    }
    gemm_one(xr, row, valid, WT, b, o, ho);
}

// ================= GATv2 building blocks =================

template <int CTRL>
__device__ __forceinline__ float dppadd_(float x) {
    int y = __builtin_amdgcn_update_dpp(0, __float_as_int(x), CTRL, 0xF, 0xF, true);
    return x + __int_as_float(y);
}

// sum across each aligned 16-lane group (all lanes get the total); VALU-only
__device__ __forceinline__ float red16_(float c) {
    c = dppadd_<0xB1>(c);   // quad_perm xor1
    c = dppadd_<0x4E>(c);   // quad_perm xor2
    c = dppadd_<0x124>(c);  // row_ror:4
    c = dppadd_<0x128>(c);  // row_ror:8
    return c;
}

template <int HAS_EF>
__device__ __forceinline__ unsigned boff_(unsigned pr) {
    return HAS_EF ? ((pr & 0xFFFFu) << 7) : pr;  // pp payloads pre-shifted
}

// Edge loop over fp16 rows; message/dot math in packed half2 (v_pk_* + v_dot2).
// No max-subtraction (scores O(+-5): fp32 exp safe). att pre-scaled by log2(e)
// and pre-converted to f16x2. slot = lane>>4 (4 edges in flight per iter),
// g = lane&15. DEPTH-4 gather pipeline (register rotation, static indices).
// Payload arrays are zero-padded 32 entries -> no clamping anywhere.
template <int HAS_EF>
__device__ __forceinline__ void gat_pass(
    const void* __restrict__ hl, const unsigned* __restrict__ pay,
    int beg, int end, int slot, int g,
    f16x2 hr01, f16x2 hr23, f16x2 att01, f16x2 att23,
    f16x2 we01, f16x2 we23,
    float& s_run, float4& acc) {
    s_run = 0.f;
    acc = make_float4(0.f, 0.f, 0.f, 0.f);
    if (beg >= end) return;
    unsigned goff = (unsigned)g * 8u;
    int p = beg + slot;
    unsigned pr0 = pay[p], pr1 = pay[p + 4], pr2 = pay[p + 8],
             pr3 = pay[p + 12], pr4 = pay[p + 16];
    uint2 u0 = ld8_(hl, boff_<HAS_EF>(pr0) + goff);
    uint2 u1 = ld8_(hl, boff_<HAS_EF>(pr1) + goff);
    uint2 u2 = ld8_(hl, boff_<HAS_EF>(pr2) + goff);
    uint2 u3 = ld8_(hl, boff_<HAS_EF>(pr3) + goff);
    int pend = end + slot;
    for (; p < pend; p += 4) {
        unsigned prn = pay[p + 20];
        uint2 un = ld8_(hl, boff_<HAS_EF>(pr4) + goff);
        f16x2 m01 = *(f16x2*)&u0.x + hr01;
        f16x2 m23 = *(f16x2*)&u0.y + hr23;
        if (HAS_EF) {
            unsigned uh = pr0 & 0xFFFF0000u;
            unsigned lbu = uh | (uh >> 16);
            f16x2 lb2 = *(f16x2*)&lbu;
            m01 = lb2 * we01 + m01;   // v_pk_fma_f16
            m23 = lb2 * we23 + m23;
        }
        m01 = __builtin_elementwise_max(m01, m01 * (_Float16)0.2f);  // leaky(0.2)
        m23 = __builtin_elementwise_max(m23, m23 * (_Float16)0.2f);
        float c = fdot2_(m01, att01, 0.f);
        c = fdot2_(m23, att23, c);
        c = red16_(c);
        float w = (p < end) ? exp2f(c) : 0.f;
        s_run += w;
        float4 h = unpk_(u0);
        acc.x = fmaf(w, h.x, acc.x);
        acc.y = fmaf(w, h.y, acc.y);
        acc.z = fmaf(w, h.z, acc.z);
        acc.w = fmaf(w, h.w, acc.w);
        pr0 = pr1; pr1 = pr2; pr2 = pr3; pr3 = pr4; pr4 = prn;
        u0 = u1; u1 = u2; u2 = u3; u3 = un;
    }
}

// cross-slot totals: pure butterfly adds
__device__ __forceinline__ void slot_merge(float& s, float4& a) {
#pragma unroll
    for (int mask = 16; mask <= 32; mask <<= 1) {
        s += __shfl_xor(s, mask, 64);
        a.x += __shfl_xor(a.x, mask, 64);
        a.y += __shfl_xor(a.y, mask, 64);
        a.z += __shfl_xor(a.z, mask, 64);
        a.w += __shfl_xor(a.w, mask, 64);
    }
}

__device__ __forceinline__ void finish_row(float s_run, float4 a,
                                           const float* __restrict__ bias, int g,
                                           float o4[4]) {
    float inv = 1.f / (s_run + 1e-16f);
    float4 b4 = *(const float4*)(bias + g * 4);
    o4[0] = fmaxf(fmaf(a.x, inv, b4.x), 0.f);
    o4[1] = fmaxf(fmaf(a.y, inv, b4.y), 0.f);
    o4[2] = fmaxf(fmaf(a.z, inv, b4.z), 0.f);
    o4[3] = fmaxf(fmaf(a.w, inv, b4.w), 0.f);
}

// In-wave GEMV row@W via LDS row broadcast: slot0 writes the 64-float row,
// each lane reads its slot's 16 j values, 64 fma, cross-slot butterfly.
__device__ __forceinline__ float4 gemv64(const float o4[4], float* __restrict__ lds_row,
                                         int slot, int g, const float* __restrict__ W) {
    if (slot == 0) *(float4*)(lds_row + 4 * g) = make_float4(o4[0], o4[1], o4[2], o4[3]);
    __asm__ volatile("" ::: "memory");
    __builtin_amdgcn_wave_barrier();
    float4 r0 = *(const float4*)(lds_row + slot * 16 + 0);
    float4 r1 = *(const float4*)(lds_row + slot * 16 + 4);
    float4 r2 = *(const float4*)(lds_row + slot * 16 + 8);
    float4 r3 = *(const float4*)(lds_row + slot * 16 + 12);
    __asm__ volatile("" ::: "memory");
    __builtin_amdgcn_wave_barrier();
    float rv[16] = {r0.x, r0.y, r0.z, r0.w, r1.x, r1.y, r1.z, r1.w,
                    r2.x, r2.y, r2.z, r2.w, r3.x, r3.y, r3.z, r3.w};
    const float* Wp = W + slot * 16 * 64 + g * 4;
    float a0 = 0.f, a1 = 0.f, a2 = 0.f, a3 = 0.f;
#pragma unroll
    for (int t = 0; t < 16; ++t) {
        float4 w4 = *(const float4*)(Wp + t * 64);
        a0 = fmaf(rv[t], w4.x, a0); a1 = fmaf(rv[t], w4.y, a1);
        a2 = fmaf(rv[t], w4.z, a2); a3 = fmaf(rv[t], w4.w, a3);
    }
    a0 += __shfl_xor(a0, 16, 64); a0 += __shfl_xor(a0, 32, 64);
    a1 += __shfl_xor(a1, 16, 64); a1 += __shfl_xor(a1, 32, 64);
    a2 += __shfl_xor(a2, 16, 64); a2 += __shfl_xor(a2, 32, 64);
    a3 += __shfl_xor(a3, 16, 64); a3 += __shfl_xor(a3, 32, 64);
    return make_float4(a0, a1, a2, a3);
}

// conv1 (products): GAT + relu + @W3l + b3l -> hl3 (fp16)
__global__ __launch_bounds__(256) void k_gat1(
    const void* __restrict__ hl, const float* __restrict__ hr,
    const int* __restrict__ offs, const unsigned* __restrict__ esrc,
    const float* __restrict__ att, const float* __restrict__ bias,
    const float* __restrict__ W2, const float* __restrict__ b2,
    void* __restrict__ out2, int ndst) {
    __shared__ float rowbuf[4][64];
    int wid = (blockIdx.x * blockDim.x + threadIdx.x) >> 6;
    if (wid >= ndst) return;
    int lane = threadIdx.x & 63, slot = lane >> 4, g = lane & 15;
    float* lrow = rowbuf[threadIdx.x >> 6];
    float4 hrf = *(const float4*)(hr + (size_t)wid * 64 + g * 4);
    f16x2 hr01 = pkc_(hrf.x, hrf.y), hr23 = pkc_(hrf.z, hrf.w);
    float4 at = *(const float4*)(att + g * 4);
    const float L2E = 1.44269504f;
    f16x2 att01 = pkc_(at.x * L2E, at.y * L2E), att23 = pkc_(at.z * L2E, at.w * L2E);
    int beg = offs[wid], end = offs[wid + 1];
    float s; float4 a;
    gat_pass<0>(hl, esrc, beg, end, slot, g, hr01, hr23, att01, att23, att01, att23, s, a);
    slot_merge(s, a);
    float o4[4];
    finish_row(s, a, bias, g, o4);
    float4 o = gemv64(o4, lrow, slot, g, W2);
    float4 bb = *(const float4*)(b2 + g * 4);
    o.x += bb.x; o.y += bb.y; o.z += bb.z; o.w += bb.w;
    if (slot == 0)
        *(uint2*)((char*)out2 + (size_t)wid * 128 + g * 8) =
            make_uint2(pkh_(o.x, o.y), pkh_(o.z, o.w));
}

// conv2 + conv3 fused per customer node
__global__ __launch_bounds__(256) void k_gat23(
    const void* __restrict__ hl2, const float* __restrict__ hr2,
    const void* __restrict__ hl3,
    const int* __restrict__ offs, const unsigned* __restrict__ epay,
    const float* __restrict__ We2, const float* __restrict__ att2, const float* __restrict__ bias2,
    const float* __restrict__ W3r, const float* __restrict__ b3r,
    const float* __restrict__ We3, const float* __restrict__ att3, const float* __restrict__ bias3,
    const float* __restrict__ Wlin, const float* __restrict__ blin,
    float* __restrict__ outp, int ndst) {
    __shared__ float rowbuf[4][64];
    int wid = (blockIdx.x * blockDim.x + threadIdx.x) >> 6;
    if (wid >= ndst) return;
    int lane = threadIdx.x & 63, slot = lane >> 4, g = lane & 15;
    float* lrow = rowbuf[threadIdx.x >> 6];
    int beg = offs[wid], end = offs[wid + 1];
    const float L2E = 1.44269504f;
    // ---- conv2 ----
    float4 hrf = *(const float4*)(hr2 + (size_t)wid * 64 + g * 4);
    f16x2 hr01 = pkc_(hrf.x, hrf.y), hr23 = pkc_(hrf.z, hrf.w);
    float4 at = *(const float4*)(att2 + g * 4);
    f16x2 att01 = pkc_(at.x * L2E, at.y * L2E), att23 = pkc_(at.z * L2E, at.w * L2E);
    float4 wef = *(const float4*)(We2 + g * 4);
    f16x2 we01 = pkc_(wef.x, wef.y), we23 = pkc_(wef.z, wef.w);
    float s; float4 a;
    gat_pass<1>(hl2, epay, beg, end, slot, g, hr01, hr23, att01, att23, we01, we23, s, a);
    slot_merge(s, a);
    float o4[4];
    finish_row(s, a, bias2, g, o4);
    float4 h3 = gemv64(o4, lrow, slot, g, W3r);
    float4 bb = *(const float4*)(b3r + g * 4);
    h3.x += bb.x; h3.y += bb.y; h3.z += bb.z; h3.w += bb.w;
    // ---- conv3 ----
    hr01 = pkc_(h3.x, h3.y); hr23 = pkc_(h3.z, h3.w);
    at = *(const float4*)(att3 + g * 4);
    att01 = pkc_(at.x * L2E, at.y * L2E); att23 = pkc_(at.z * L2E, at.w * L2E);
    wef = *(const float4*)(We3 + g * 4);
    we01 = pkc_(wef.x, wef.y); we23 = pkc_(wef.z, wef.w);
    gat_pass<1>(hl3, epay, beg, end, slot, g, hr01, hr23, att01, att23, we01, we23, s, a);
    slot_merge(s, a);
    finish_row(s, a, bias3, g, o4);
    float4 o = gemv64(o4, lrow, slot, g, Wlin);
    float4 bl = *(const float4*)(blin + g * 4);
    o.x += bl.x; o.y += bl.y; o.z += bl.z; o.w += bl.w;
    if (slot == 0) *(float4*)(outp + (size_t)wid * 64 + g * 4) = o;
}

// ================= launch =================

extern "C" void kernel_launch(void* const* d_in, const int* in_sizes, int n_in,
                              void* d_out, int out_size, void* d_ws, size_t ws_size,
                              hipStream_t stream) {
    const float* x_p = (const float*)d_in[0];
    const float* x_c = (const float*)d_in[1];
    const float* elab_in = (const float*)d_in[2];
    const int* src_pp = (const int*)d_in[3];
    const int* dst_pp = (const int*)d_in[4];
    const int* src_pc = (const int*)d_in[5];
    const int* dst_pc = (const int*)d_in[6];
    const float* W1l = (const float*)d_in[7];
    const float* b1l = (const float*)d_in[8];
    const float* W1r = (const float*)d_in[9];
    const float* b1r = (const float*)d_in[10];
    const float* att1 = (const float*)d_in[11];
    const float* bias1 = (const float*)d_in[12];
    const float* W2l = (const float*)d_in[13];
    const float* b2l = (const float*)d_in[14];
    const float* W2r = (const float*)d_in[15];
    const float* b2r = (const float*)d_in[16];
    const float* We2 = (const float*)d_in[17];
    const float* att2 = (const float*)d_in[18];
    const float* bias2 = (const float*)d_in[19];
    const float* W3l = (const float*)d_in[20];
    const float* b3l = (const float*)d_in[21];
    const float* W3r = (const float*)d_in[22];
    const float* b3r = (const float*)d_in[23];
    const float* We3 = (const float*)d_in[24];
    const float* att3 = (const float*)d_in[25];
    const float* bias3 = (const float*)d_in[26];
    const float* Wlin = (const float*)d_in[27];
    const float* blin = (const float*)d_in[28];
    float* out = (float*)d_out;

    const int NP = in_sizes[0] / 64;
    const int NC = in_sizes[1] / 64;
    const int EPP = in_sizes[3];
    const int EPC = in_sizes[5];
    const int E1 = EPP + NP;
    const int NB1 = ceil_div(NP, 512), NB2 = ceil_div(NC, 512);

    // workspace layout (256B-aligned chunks)
    char* w = (char*)d_ws;
    auto alloc = [&](size_t bytes) { char* r = w; w += (bytes + 255) & ~(size_t)255; return r; };
    void* hl1 = alloc((size_t)NP * 128);       // fp16
    void* hl2 = alloc((size_t)NP * 128);       // fp16
    void* hl3 = alloc((size_t)NP * 128);       // fp16 (conv1-fused output)
    float* hr1 = (float*)alloc((size_t)NP * 256);
    float* hr2 = (float*)alloc((size_t)NC * 256);
    float* wt = (float*)alloc(4 * 4096 * 4);
    unsigned* epay = (unsigned*)alloc((size_t)(EPC + 32) * 4);
    unsigned* e1src = (unsigned*)alloc((size_t)(E1 + 32) * 4);
    uint2* stg1 = (uint2*)alloc((size_t)E1 * 8);
    uint2* stg2 = (uint2*)alloc((size_t)EPC * 8);
    int* off1 = (int*)alloc((size_t)(NP + 1) * 4);
    int* off2 = (int*)alloc((size_t)(NC + 1) * 4);
    int* btot1 = (int*)alloc(256 * 4);
    int* btot2 = (int*)alloc(256 * 4);
    int* bbase1 = (int*)alloc(260 * 4);
    int* bbase2 = (int*)alloc(260 * 4);
    int* bcur1 = (int*)alloc(256 * 4);
    int* bcur2 = (int*)alloc(256 * 4);

    int chunksH = ceil_div(EPC > EPP ? EPC : EPP, PART_CHUNK);
    int maxEp = EPC > E1 ? EPC : E1;

    (void)hipMemsetAsync(btot1, 0, 256 * 4, stream);
    (void)hipMemsetAsync(btot2, 0, 256 * 4, stream);

    k_transpose_all<<<dim3(64, 4), 64, 0, stream>>>(W1l, W1r, W2l, W2r, wt);

    k_bhist<<<dim3(chunksH, 2), 256, 0, stream>>>(dst_pp, EPP, dst_pc, EPC, btot1, btot2);
    k_bscan<<<dim3(1, 2), 256, 0, stream>>>(NP, NB1, btot1, bbase1, bcur1,
                                            NC, NB2, btot2, bbase2, bcur2);
    k_partA<<<dim3(ceil_div(maxEp, PART_CHUNK), 2), 256, 0, stream>>>(
        NP, src_pp, dst_pp, E1, src_pc, dst_pc, elab_in, EPC, bcur1, bcur2, stg1, stg2);
    k_partB2<<<NB1 + NB2, 512, 0, stream>>>(
        NB1, NP, bbase1, stg1, e1src, off1, E1,
        NC, bbase2, stg2, epay, off2, EPC);

    // fused input transforms: hl1 = x_p@W1l (h), hr1 = x_p@W1r (f), hl2 = x_p@W2l (h), hr2 = x_c@W2r (f)
    int tp = ceil_div(NP, 64), tc = ceil_div(NC, 64);
    GemmJobs J;
    J.x[0] = x_p; J.WT[0] = wt + 0 * 4096; J.b[0] = b1l; J.o[0] = hl1; J.n[0] = NP; J.half_out[0] = 1;
    J.x[1] = x_p; J.WT[1] = wt + 1 * 4096; J.b[1] = b1r; J.o[1] = hr1; J.n[1] = NP; J.half_out[1] = 0;
    J.x[2] = x_p; J.WT[2] = wt + 2 * 4096; J.b[2] = b2l; J.o[2] = hl2; J.n[2] = NP; J.half_out[2] = 1;
    J.x[3] = x_c; J.WT[3] = wt + 3 * 4096; J.b[3] = b2r; J.o[3] = hr2; J.n[3] = NC; J.half_out[3] = 0;
    J.tend[0] = tp; J.tend[1] = 2 * tp; J.tend[2] = 3 * tp; J.tend[3] = 3 * tp + tc;
    k_gemm_all<<<ceil_div(J.tend[3] * 64, 256), 256, 0, stream>>>(J);

    // conv1 -> (relu -> @W3l + b3l) -> hl3 (fp16)
    k_gat1<<<ceil_div(NP * 64, 256), 256, 0, stream>>>(
        hl1, hr1, off1, e1src, att1, bias1, W3l, b3l, hl3, NP);

    // conv2+conv3 fused -> d_out
    k_gat23<<<ceil_div(NC * 64, 256), 256, 0, stream>>>(
        hl2, hr2, hl3, off2, epay, We2, att2, bias2, W3r, b3r,
        We3, att3, bias3, Wlin, blin, out, NC);
}